// Round 1
// baseline (719.743 us; speedup 1.0000x reference)
//
#include <hip/hip_runtime.h>
#include <math.h>

#define NB 32
#define NN 1024
#define ND 1024
#define NO 1024
#define NH 512
#define NR 64

// ---------------- workspace offsets (in floats) ----------------
// NOTE: colsum partials (32*16*1024 = 524288) alias OFF_PG: k0/k1 finish
// before the wg GEMM writes pg_ (stream-ordered), sizes match exactly.
#define OFF_PM     0u         /* 32768 */
#define OFF_PMSQ   32768u     /* 32 */
#define OFF_ROWSQ  32800u     /* 32768 */
#define OFF_G      65568u     /* 32768 */
#define OFF_H0     98336u     /* 32768 */
#define OFF_H1     131104u    /* 16384 */
#define OFF_LOCAL  147488u    /* 16384 */
#define OFF_P1     163872u    /* 131072  w1 partials (8*32*512) */
#define OFF_P2     294944u    /* 65536   w2 partials (4*32*512) */
#define OFF_PG     360480u    /* 524288  wg partials (4*32*4096)  == colsum part */
#define OFF_PL     884768u    /* 524288 */
#define OFF_AG     1409056u   /* 131072 */
#define OFF_AL     1540128u   /* 131072 */
#define OFF_MASK   1671200u   /* 2048 */
#define OFF_GAINS  1673248u   /* 2048 */
#define OFF_SCAL   1675296u   /* 128 */
#define OFF_MFIN   1675424u   /* 131072 */
#define OFF_C      1806496u   /* 2097152 */
#define OFF_PROJ   3903648u   /* 2097152 */
#define OFF_BT     6000800u   /* 65536  basisT (1024 x 64) */
/* total 6066336 floats ~= 24.27 MB (<= proven 24.5 MB) */

// ---------------- kT: basisT[d][r] = basis[r][d]  (64x1024 -> 1024x64) ----------------
__global__ __launch_bounds__(256) void kT_basis(const float* __restrict__ basis, float* __restrict__ basisT){
  __shared__ float s[64][65];
  int d0 = blockIdx.x*64;
  int tid = threadIdx.x;
  #pragma unroll
  for(int i=0;i<16;i++){
    int idx = i*256 + tid;          // 0..4095
    int r = idx>>6, dl = idx&63;
    s[r][dl] = basis[(size_t)r*ND + d0 + dl];
  }
  __syncthreads();
  #pragma unroll
  for(int i=0;i<16;i++){
    int idx = i*256 + tid;
    int dl = idx>>6, r = idx&63;
    basisT[(size_t)(d0+dl)*64 + r] = s[r][dl];
  }
}

// ---------------- K0: column sums of pt = x[:,1:,:] + rowsq (float4, 16 n-segments) ----------------
__global__ __launch_bounds__(256) void k0_colsum(const float* __restrict__ x, float* __restrict__ part,
    float* __restrict__ rowsq){
  __shared__ float red[4][64];
  int tid = threadIdx.x;
  int nseg = blockIdx.x, b = blockIdx.y;
  int d4 = tid*4;
  int lane = tid & 63, wv = tid >> 6;
  const float* xp = x + (size_t)b*NN*ND + d4;
  int nstart = nseg*64; if(nseg==0) nstart = 1;
  int nend = nseg*64 + 64;
  float sx=0.f, sy=0.f, sz=0.f, sw=0.f;
  #pragma unroll 4
  for(int n=nstart; n<nend; n++){
    float4 v = *(const float4*)&xp[(size_t)n*ND];
    sx+=v.x; sy+=v.y; sz+=v.z; sw+=v.w;
    float s = v.x*v.x + v.y*v.y + v.z*v.z + v.w*v.w;
    #pragma unroll
    for(int o=32;o>0;o>>=1) s += __shfl_down(s, o);
    if(lane==0) red[wv][n - nseg*64] = s;
  }
  *(float4*)&part[(size_t)(b*16+nseg)*1024 + d4] = make_float4(sx,sy,sz,sw);
  __syncthreads();
  if(tid < 64 && !(nseg==0 && tid==0)){
    rowsq[b*1024 + nseg*64 + tid] = red[0][tid]+red[1][tid]+red[2][tid]+red[3][tid];
  }
}

// ---------------- K1: pm = colsum/1023, pmsq[b] = sum(pm^2)/D ----------------
__global__ __launch_bounds__(256) void k1_pmreduce(const float* __restrict__ part, float* __restrict__ pm, float* __restrict__ pmsq){
  __shared__ float red[256];
  int b = blockIdx.x, tid = threadIdx.x;
  float acc = 0.f;
  #pragma unroll
  for(int i=0;i<4;i++){
    int d = i*256 + tid;
    float s = 0.f;
    #pragma unroll
    for(int ks=0;ks<16;ks++) s += part[(size_t)(b*16+ks)*1024 + d];
    float p = s * (1.0f/1023.0f);
    pm[b*1024+d] = p;
    acc += p*p;
  }
  red[tid] = acc; __syncthreads();
  for(int o=128;o>0;o>>=1){ if(tid<o) red[tid]+=red[tid+o]; __syncthreads(); }
  if(tid==0) pmsq[b] = red[0]*(1.0f/1024.0f);
}

// ---------------- K2: register GEMM proj = x @ basisT; G = x . pm ----------------
// 1024 blocks x 256 threads; block = 32 rows x 64 cols; thread = 2 rows x 4 cols.
// No LDS, no syncs: basisT (256KB) is L2-resident; x streams once from HBM.
__global__ __launch_bounds__(256) void k2_proj(const float* __restrict__ x, const float* __restrict__ bT,
    const float* __restrict__ pm, float* __restrict__ proj, float* __restrict__ G){
  int tid = threadIdx.x;
  int row0 = blockIdx.x*32;          // global row (b*1024 + n)
  int b = row0 >> 10;
  int rg = tid>>4, cg = tid&15;
  int r0 = row0 + rg*2;
  const float* xr0 = x + (size_t)r0*ND;
  const float* xr1 = xr0 + ND;
  const float* pmb = pm + (size_t)b*ND;
  const float* bc  = bT + cg*4;
  float4 acc0 = make_float4(0.f,0.f,0.f,0.f);
  float4 acc1 = make_float4(0.f,0.f,0.f,0.f);
  float g0 = 0.f, g1 = 0.f;
  #pragma unroll 2
  for(int k=0;k<ND;k+=4){
    float4 a0 = *(const float4*)&xr0[k];
    float4 a1 = *(const float4*)&xr1[k];
    float4 p  = *(const float4*)&pmb[k];
    float4 b0 = *(const float4*)&bc[(size_t)(k+0)*64];
    float4 b1 = *(const float4*)&bc[(size_t)(k+1)*64];
    float4 b2 = *(const float4*)&bc[(size_t)(k+2)*64];
    float4 b3 = *(const float4*)&bc[(size_t)(k+3)*64];
    float ar0[4]={a0.x,a0.y,a0.z,a0.w};
    float ar1[4]={a1.x,a1.y,a1.z,a1.w};
    float pr[4]={p.x,p.y,p.z,p.w};
    float4 bb[4]={b0,b1,b2,b3};
    #pragma unroll
    for(int j=0;j<4;j++){
      acc0.x += ar0[j]*bb[j].x; acc0.y += ar0[j]*bb[j].y;
      acc0.z += ar0[j]*bb[j].z; acc0.w += ar0[j]*bb[j].w;
      acc1.x += ar1[j]*bb[j].x; acc1.y += ar1[j]*bb[j].y;
      acc1.z += ar1[j]*bb[j].z; acc1.w += ar1[j]*bb[j].w;
      g0 += ar0[j]*pr[j];
      g1 += ar1[j]*pr[j];
    }
  }
  *(float4*)&proj[(size_t)r0*NR + cg*4]     = acc0;
  *(float4*)&proj[(size_t)(r0+1)*NR + cg*4] = acc1;
  if(cg==0){ G[r0] = g0; G[r0+1] = g1; }
}

// ---------------- K3: scores, top-4, detail, LayerNorm -> h0 ----------------
__global__ __launch_bounds__(256) void k3_detail(const float* __restrict__ x, const float* __restrict__ rowsq,
    const float* __restrict__ G, const float* __restrict__ pmsq,
    const float* __restrict__ gamma_, const float* __restrict__ beta_, float* __restrict__ h0){
  __shared__ float sc[1024];
  __shared__ float rv[256];
  __shared__ int ri[256];
  __shared__ int topi[4];
  __shared__ float mred[256];
  int b = blockIdx.x, tid = threadIdx.x;
  float ps = pmsq[b];
  const float invD = 1.0f/1024.0f;
  for(int n=tid;n<1024;n+=256)
    sc[n] = (n==0) ? -INFINITY : (rowsq[b*1024+n] - 2.0f*G[b*1024+n])*invD + ps;
  __syncthreads();
  for(int t=0;t<4;t++){
    float bv = -INFINITY; int bi = 0x7fffffff;
    for(int n=tid;n<1024;n+=256){
      float v = sc[n];
      if(v>bv || (v==bv && n<bi)){ bv=v; bi=n; }
    }
    rv[tid]=bv; ri[tid]=bi;
    __syncthreads();
    for(int o=128;o>0;o>>=1){
      if(tid<o){
        float v=rv[tid+o]; int ii=ri[tid+o];
        if(v>rv[tid] || (v==rv[tid] && ii<ri[tid])){ rv[tid]=v; ri[tid]=ii; }
      }
      __syncthreads();
    }
    if(tid==0){ topi[t]=ri[0]; sc[ri[0]] = -INFINITY; }
    __syncthreads();
  }
  int i0=topi[0], i1=topi[1], i2=topi[2], i3=topi[3];
  float dv[4]; float dsum=0.f;
  #pragma unroll
  for(int jj=0;jj<4;jj++){
    int d = tid + jj*256;
    float v = 0.25f*(x[((size_t)(b*NN+i0))*ND+d] + x[((size_t)(b*NN+i1))*ND+d]
                   + x[((size_t)(b*NN+i2))*ND+d] + x[((size_t)(b*NN+i3))*ND+d]);
    dv[jj]=v; dsum+=v;
  }
  mred[tid]=dsum; __syncthreads();
  for(int o=128;o>0;o>>=1){ if(tid<o) mred[tid]+=mred[tid+o]; __syncthreads(); }
  float mu = mred[0]*invD;
  __syncthreads();
  float vs=0.f;
  #pragma unroll
  for(int jj=0;jj<4;jj++){ float t2=dv[jj]-mu; vs+=t2*t2; }
  mred[tid]=vs; __syncthreads();
  for(int o=128;o>0;o>>=1){ if(tid<o) mred[tid]+=mred[tid+o]; __syncthreads(); }
  float var = mred[0]*invD;
  float rstd = rsqrtf(var + 1e-5f);
  #pragma unroll
  for(int jj=0;jj<4;jj++){
    int d = tid + jj*256;
    h0[b*1024+d] = (dv[jj]-mu)*rstd*gamma_[d] + beta_[d];
  }
}

// ---------------- generic small GEMM (32 x Kd) @ (Kd x Ncols), k-split partials ----------------
__global__ __launch_bounds__(256) void gemm32_partial(const float* __restrict__ V, const float* __restrict__ W,
      float* __restrict__ part, int Kd, int Ncols){
  __shared__ __align__(16) float Vs[128][36];
  int col = blockIdx.x*256 + threadIdx.x;
  int k0 = blockIdx.y*128;
  for(int i=threadIdx.x; i<4096; i+=256){ int r=i>>7, k=i&127; Vs[k][r] = V[(size_t)r*Kd + k0 + k]; }
  __syncthreads();
  float acc[32];
  #pragma unroll
  for(int r=0;r<32;r++) acc[r]=0.f;
  #pragma unroll 4
  for(int k=0;k<128;k++){
    float wv = W[(size_t)(k0+k)*Ncols + col];
    #pragma unroll
    for(int r4=0;r4<8;r4++){
      float4 v = *(const float4*)&Vs[k][r4*4];
      acc[r4*4+0]+=v.x*wv; acc[r4*4+1]+=v.y*wv; acc[r4*4+2]+=v.z*wv; acc[r4*4+3]+=v.w*wv;
    }
  }
  #pragma unroll
  for(int r=0;r<32;r++) part[((size_t)(blockIdx.y*32 + r))*Ncols + col] = acc[r];
}

// ---------------- reductions of partials ----------------
__global__ __launch_bounds__(256) void k_red_gelu(const float* __restrict__ part, const float* __restrict__ b1, float* __restrict__ h1){
  int id = blockIdx.x*256 + threadIdx.x;  // 16384
  int b_ = id >> 9, j = id & 511;
  float s = b1[j];
  #pragma unroll
  for(int ks=0;ks<8;ks++) s += part[(size_t)(ks*32+b_)*512 + j];
  h1[id] = 0.5f*s*(1.0f + erff(s*0.70710678118654752440f));
}
__global__ __launch_bounds__(256) void k_red_local(const float* __restrict__ part, const float* __restrict__ b2, float* __restrict__ lcl){
  int id = blockIdx.x*256 + threadIdx.x;  // 16384
  int b_ = id >> 9, j = id & 511;
  float s = b2[j];
  #pragma unroll
  for(int ks=0;ks<4;ks++) s += part[(size_t)(ks*32+b_)*512 + j];
  lcl[id] = s;
}
__global__ __launch_bounds__(256) void k_red_gl(const float* __restrict__ pg, const float* __restrict__ pl,
    const float* __restrict__ bg, const float* __restrict__ bl, float* __restrict__ Ag, float* __restrict__ Al){
  int id = blockIdx.x*256 + threadIdx.x;  // 131072
  int c = id & 4095;
  int b_ = id >> 12;
  float sg = bg[c], sl = bl[c];
  #pragma unroll
  for(int ks=0;ks<4;ks++){
    sg += pg[(size_t)(ks*32 + b_)*4096 + c];
    sl += pl[(size_t)(ks*32 + b_)*4096 + c];
  }
  Ag[id] = sg; Al[id] = sl;
}

// ---------------- heads: mode_mask, gains, alpha/beta/gate ----------------
// 1024 threads: 16 waves each own a 64-row k-slice of wm/wgain (coalesced
// 256B row loads, unroll-8 => many loads in flight), LDS tree-reduce.
__global__ __launch_bounds__(1024) void k_heads(const float* __restrict__ context, const float* __restrict__ lcl,
    const float* __restrict__ wm, const float* __restrict__ bm,
    const float* __restrict__ wgain, const float* __restrict__ bgain,
    const float* __restrict__ wgate, const float* __restrict__ bgate,
    const float* __restrict__ wa, const float* __restrict__ ba,
    const float* __restrict__ wb, const float* __restrict__ bb,
    float* __restrict__ mask, float* __restrict__ gains, float* __restrict__ scal){
  __shared__ float fs[1024];
  __shared__ float redm[16][64];
  __shared__ float redg[16][64];
  __shared__ float wra[16], wrb[16], wrg[16];
  int b = blockIdx.x, tid = threadIdx.x;
  fs[tid] = (tid < 512) ? context[b*512 + tid] : lcl[b*512 + tid - 512];
  __syncthreads();
  int j = tid & 63, kq = tid >> 6;   // lane, wave
  const float* wmp = wm    + (size_t)(kq*64)*64 + j;
  const float* wgp = wgain + (size_t)(kq*64)*64 + j;
  float am = 0.f, ag = 0.f;
  #pragma unroll 8
  for(int k=0;k<64;k++){
    float f = fs[kq*64 + k];
    am += f * wmp[k*64];
    ag += f * wgp[k*64];
  }
  redm[kq][j] = am; redg[kq][j] = ag;
  // scalar head partials (wa, wb, wgate are 1024-vectors)
  float f = fs[tid];
  float pa = f*wa[tid], pb = f*wb[tid], pg = f*wgate[tid];
  #pragma unroll
  for(int o=32;o>0;o>>=1){
    pa += __shfl_down(pa, o);
    pb += __shfl_down(pb, o);
    pg += __shfl_down(pg, o);
  }
  if(j == 0){ wra[kq]=pa; wrb[kq]=pb; wrg[kq]=pg; }
  __syncthreads();
  for(int o=8;o>0;o>>=1){
    if(kq < o){ redm[kq][j] += redm[kq+o][j]; redg[kq][j] += redg[kq+o][j]; }
    __syncthreads();
  }
  if(tid < 64){
    float m = redm[0][tid] + bm[tid];
    mask[b*64+tid] = 1.0f/(1.0f+expf(-m));
    float g = redg[0][tid] + bgain[tid];
    gains[b*64+tid] = 1.0f + 0.1f*tanhf(g);
  }
  if(tid == 0){
    float sa=0.f, sb=0.f, sg=0.f;
    #pragma unroll
    for(int i=0;i<16;i++){ sa+=wra[i]; sb+=wrb[i]; sg+=wrg[i]; }
    scal[b*4+0] = 0.5f/(1.0f+expf(-(sa+ba[0])));    // alpha
    scal[b*4+1] = 0.25f*tanhf(sb+bb[0]);            // beta
    scal[b*4+2] = 1.0f/(1.0f+expf(-(sg+bgate[0]))); // gate
  }
}

// ---------------- K7: mg/ml, comm, omega, expm (scaling+squaring Taylor), Mfin ----------------
__global__ __launch_bounds__(1024) void k7_expm(const float* __restrict__ Ag, const float* __restrict__ Al,
    const float* __restrict__ mask, const float* __restrict__ gains, const float* __restrict__ scal,
    float* __restrict__ Mfin){
  __shared__ __align__(16) float B0s[64][66];
  __shared__ __align__(16) float B1s[64][66];
  __shared__ __align__(16) float B2s[64][66];
  __shared__ float msks[64];
  __shared__ float colsum[64];
  __shared__ int ssh;
  int b = blockIdx.x, tid = threadIdx.x;
  int ig = tid>>5, jg = tid&31;
  int i0 = ig*2, j0 = jg*2;
  if(tid<64) msks[tid] = mask[b*64+tid];
  __syncthreads();
  float alpha = scal[b*4+0], bta = scal[b*4+1], gate = scal[b*4+2];
  const float* ag = Ag + b*4096;
  const float* al = Al + b*4096;
  #pragma unroll
  for(int di=0;di<2;di++){
    #pragma unroll
    for(int dj=0;dj<2;dj++){
      int i=i0+di, jx=j0+dj;
      float mm_ = msks[i]*msks[jx]*0.5f;
      B0s[i][jx] = mm_*(ag[i*64+jx]-ag[jx*64+i]);   // mg
      B1s[i][jx] = mm_*(al[i*64+jx]-al[jx*64+i]);   // ml
    }
  }
  __syncthreads();
  // B2 = ml@mg - mg@ml
  {
    float c00=0.f,c01=0.f,c10=0.f,c11=0.f;
    #pragma unroll 4
    for(int k=0;k<64;k++){
      float a0=B1s[i0][k], a1=B1s[i0+1][k];
      float m0=B0s[i0][k], m1=B0s[i0+1][k];
      float2 u = *(const float2*)&B0s[k][j0];
      float2 w = *(const float2*)&B1s[k][j0];
      c00 += a0*u.x - m0*w.x;  c01 += a0*u.y - m0*w.y;
      c10 += a1*u.x - m1*w.x;  c11 += a1*u.y - m1*w.y;
    }
    B2s[i0][j0]=c00; B2s[i0][j0+1]=c01; B2s[i0+1][j0]=c10; B2s[i0+1][j0+1]=c11;
  }
  __syncthreads();
  const float bc = bta*(1.0f/12.0f);
  #pragma unroll
  for(int di=0;di<2;di++){
    #pragma unroll
    for(int dj=0;dj<2;dj++){
      int i=i0+di, jx=j0+dj;
      B0s[i][jx] = alpha*0.5f*(B0s[i][jx]+B1s[i][jx]) + bc*B2s[i][jx];  // omega
    }
  }
  __syncthreads();
  if(tid<64){
    float s=0.f;
    for(int i=0;i<64;i++) s += fabsf(B0s[i][tid]);
    colsum[tid]=s;
  }
  __syncthreads();
  if(tid==0){
    float m=0.f;
    for(int jx=0;jx<64;jx++) m = fmaxf(m, colsum[jx]);
    int s=0;
    while(m>0.5f && s<30){ m*=0.5f; s++; }
    ssh = s;
  }
  __syncthreads();
  int sh = ssh;
  float scl = ldexpf(1.0f, -sh);
  #pragma unroll
  for(int di=0;di<2;di++){
    #pragma unroll
    for(int dj=0;dj<2;dj++){ int i=i0+di,jx=j0+dj; B0s[i][jx]*=scl; }
  }
  __syncthreads();
  // Horner: P = I + A/8
  #pragma unroll
  for(int di=0;di<2;di++){
    #pragma unroll
    for(int dj=0;dj<2;dj++){
      int i=i0+di, jx=j0+dj;
      B1s[i][jx] = ((i==jx)?1.0f:0.0f) + B0s[i][jx]*0.125f;
    }
  }
  __syncthreads();
  for(int kk=7;kk>=1;kk--){
    float c00=0.f,c01=0.f,c10=0.f,c11=0.f;
    #pragma unroll 4
    for(int k=0;k<64;k++){
      float a0=B0s[i0][k], a1=B0s[i0+1][k];
      float2 u = *(const float2*)&B1s[k][j0];
      c00+=a0*u.x; c01+=a0*u.y; c10+=a1*u.x; c11+=a1*u.y;
    }
    B2s[i0][j0]=c00; B2s[i0][j0+1]=c01; B2s[i0+1][j0]=c10; B2s[i0+1][j0+1]=c11;
    __syncthreads();
    float inv = 1.0f/(float)kk;
    #pragma unroll
    for(int di=0;di<2;di++){
      #pragma unroll
      for(int dj=0;dj<2;dj++){
        int i=i0+di, jx=j0+dj;
        B1s[i][jx] = ((i==jx)?1.0f:0.0f) + B2s[i][jx]*inv;
      }
    }
    __syncthreads();
  }
  float (*Q)[66] = B1s; float (*T)[66] = B2s;
  for(int t=0;t<sh;t++){
    float c00=0.f,c01=0.f,c10=0.f,c11=0.f;
    #pragma unroll 4
    for(int k=0;k<64;k++){
      float a0=Q[i0][k], a1=Q[i0+1][k];
      float2 u = *(const float2*)&Q[k][j0];
      c00+=a0*u.x; c01+=a0*u.y; c10+=a1*u.x; c11+=a1*u.y;
    }
    T[i0][j0]=c00; T[i0][j0+1]=c01; T[i0+1][j0]=c10; T[i0+1][j0+1]=c11;
    __syncthreads();
    float (*tmp)[66]=Q; Q=T; T=tmp;
  }
  float g0 = gains[b*64+j0], g1 = gains[b*64+j0+1];
  float* mf = Mfin + b*4096;
  #pragma unroll
  for(int di=0;di<2;di++){
    int i=i0+di;
    float2 v;
    v.x = gate*(Q[i][j0]*g0   - ((i==j0)?1.0f:0.0f));
    v.y = gate*(Q[i][j0+1]*g1 - ((i==j0+1)?1.0f:0.0f));
    *(float2*)&mf[i*64+j0] = v;
  }
}

// ---------------- K8: C_b = Mfin_b @ output_basis ----------------
__global__ __launch_bounds__(256) void k8_cmat(const float* __restrict__ Mfin, const float* __restrict__ ob, float* __restrict__ C){
  __shared__ __align__(16) float MT[64][68];
  int b = blockIdx.y; int o0 = blockIdx.x*128;
  int tid = threadIdx.x;
  for(int idx=tid; idx<4096; idx+=256){ int i=idx>>6, k=idx&63; MT[k][i] = Mfin[b*4096+idx]; }
  __syncthreads();
  int cg = tid&31, rg = tid>>5;
  float acc[8][4];
  #pragma unroll
  for(int r=0;r<8;r++){ acc[r][0]=0.f; acc[r][1]=0.f; acc[r][2]=0.f; acc[r][3]=0.f; }
  for(int k=0;k<64;k++){
    float4 bv = *(const float4*)&ob[(size_t)k*NO + o0 + cg*4];
    float4 a0 = *(const float4*)&MT[k][rg*8];
    float4 a1 = *(const float4*)&MT[k][rg*8+4];
    float arr[8]={a0.x,a0.y,a0.z,a0.w,a1.x,a1.y,a1.z,a1.w};
    #pragma unroll
    for(int r=0;r<8;r++){
      acc[r][0]+=arr[r]*bv.x; acc[r][1]+=arr[r]*bv.y; acc[r][2]+=arr[r]*bv.z; acc[r][3]+=arr[r]*bv.w;
    }
  }
  #pragma unroll
  for(int r=0;r<8;r++){
    *(float4*)&C[((size_t)(b*64 + rg*8+r))*NO + o0 + cg*4] = make_float4(acc[r][0],acc[r][1],acc[r][2],acc[r][3]);
  }
}

// ---------------- K9: out_b = proj_b @ C_b ----------------
__global__ __launch_bounds__(256) void k9_out(const float* __restrict__ proj, const float* __restrict__ C, float* __restrict__ out){
  __shared__ __align__(16) float PT[64][132];
  __shared__ __align__(16) float CS[64][68];
  int b = blockIdx.z; int row0 = blockIdx.y*128; int o0 = blockIdx.x*64;
  int tid = threadIdx.x;
  #pragma unroll
  for(int i=0;i<8;i++){
    int f = tid + 256*i; int r = f>>4; int kv = f&15;
    float4 v = *(const float4*)&proj[((size_t)(b*NN + row0 + r))*NR + kv*4];
    PT[kv*4+0][r]=v.x; PT[kv*4+1][r]=v.y; PT[kv*4+2][r]=v.z; PT[kv*4+3][r]=v.w;
  }
  #pragma unroll
  for(int i=0;i<4;i++){
    int f = tid + 256*i; int k = f>>4; int kv = f&15;
    *(float4*)&CS[k][kv*4] = *(const float4*)&C[((size_t)(b*NR + k))*NO + o0 + kv*4];
  }
  __syncthreads();
  int rg = tid>>4, cg = tid&15;
  float acc[8][4];
  #pragma unroll
  for(int r=0;r<8;r++){ acc[r][0]=0.f; acc[r][1]=0.f; acc[r][2]=0.f; acc[r][3]=0.f; }
  #pragma unroll 8
  for(int k=0;k<64;k++){
    float4 bv = *(const float4*)&CS[k][cg*4];
    float4 a0 = *(const float4*)&PT[k][rg*8];
    float4 a1 = *(const float4*)&PT[k][rg*8+4];
    float arr[8]={a0.x,a0.y,a0.z,a0.w,a1.x,a1.y,a1.z,a1.w};
    #pragma unroll
    for(int r=0;r<8;r++){
      acc[r][0]+=arr[r]*bv.x; acc[r][1]+=arr[r]*bv.y; acc[r][2]+=arr[r]*bv.z; acc[r][3]+=arr[r]*bv.w;
    }
  }
  #pragma unroll
  for(int r=0;r<8;r++){
    *(float4*)&out[((size_t)(b*NN + row0 + rg*8 + r))*NO + o0 + cg*4] =
        make_float4(acc[r][0],acc[r][1],acc[r][2],acc[r][3]);
  }
}

extern "C" void kernel_launch(void* const* d_in, const int* in_sizes, int n_in,
                              void* d_out, int out_size, void* d_ws, size_t ws_size,
                              hipStream_t stream) {
  (void)in_sizes; (void)n_in; (void)out_size; (void)ws_size;
  const float* x       = (const float*)d_in[0];
  const float* context = (const float*)d_in[1];
  const float* ibasis  = (const float*)d_in[2];
  const float* obasis  = (const float*)d_in[3];
  const float* lng     = (const float*)d_in[4];
  const float* lnb     = (const float*)d_in[5];
  const float* w1      = (const float*)d_in[6];
  const float* b1      = (const float*)d_in[7];
  const float* w2      = (const float*)d_in[8];
  const float* b2      = (const float*)d_in[9];
  const float* wg      = (const float*)d_in[10];
  const float* bg      = (const float*)d_in[11];
  const float* wl      = (const float*)d_in[12];
  const float* bl      = (const float*)d_in[13];
  const float* wm      = (const float*)d_in[14];
  const float* bm      = (const float*)d_in[15];
  const float* wgain   = (const float*)d_in[16];
  const float* bgain   = (const float*)d_in[17];
  const float* wgate   = (const float*)d_in[18];
  const float* bgate   = (const float*)d_in[19];
  const float* wa      = (const float*)d_in[20];
  const float* ba      = (const float*)d_in[21];
  const float* wb      = (const float*)d_in[22];
  const float* bb      = (const float*)d_in[23];
  float* out = (float*)d_out;
  float* ws  = (float*)d_ws;

  float* pm    = ws + OFF_PM;
  float* pmsq  = ws + OFF_PMSQ;
  float* rowsq = ws + OFF_ROWSQ;
  float* G     = ws + OFF_G;
  float* h0    = ws + OFF_H0;
  float* h1    = ws + OFF_H1;
  float* lcl   = ws + OFF_LOCAL;
  float* p1    = ws + OFF_P1;
  float* p2    = ws + OFF_P2;
  float* pg_   = ws + OFF_PG;
  float* part  = ws + OFF_PG;   // alias: consumed by k1 before pg_ is written
  float* pl_   = ws + OFF_PL;
  float* Ag    = ws + OFF_AG;
  float* Al    = ws + OFF_AL;
  float* mask  = ws + OFF_MASK;
  float* gains = ws + OFF_GAINS;
  float* scal  = ws + OFF_SCAL;
  float* Mfin  = ws + OFF_MFIN;
  float* Cb    = ws + OFF_C;
  float* proj  = ws + OFF_PROJ;
  float* bT    = ws + OFF_BT;

  kT_basis<<<16,256,0,stream>>>(ibasis, bT);
  k0_colsum<<<dim3(16,NB),256,0,stream>>>(x, part, rowsq);
  k1_pmreduce<<<NB,256,0,stream>>>(part, pm, pmsq);
  k2_proj<<<1024,256,0,stream>>>(x, bT, pm, proj, G);
  k3_detail<<<NB,256,0,stream>>>(x, rowsq, G, pmsq, lng, lnb, h0);
  gemm32_partial<<<dim3(2,8),256,0,stream>>>(h0, w1, p1, 1024, 512);
  k_red_gelu<<<64,256,0,stream>>>(p1, b1, h1);
  gemm32_partial<<<dim3(2,4),256,0,stream>>>(h1, w2, p2, 512, 512);
  k_red_local<<<64,256,0,stream>>>(p2, b2, lcl);
  gemm32_partial<<<dim3(16,4),256,0,stream>>>(context, wg, pg_, 512, 4096);
  gemm32_partial<<<dim3(16,4),256,0,stream>>>(lcl, wl, pl_, 512, 4096);
  k_red_gl<<<512,256,0,stream>>>(pg_, pl_, bg, bl, Ag, Al);
  k_heads<<<NB,1024,0,stream>>>(context, lcl, wm, bm, wgain, bgain, wgate, bgate, wa, ba, wb, bb, mask, gains, scal);
  k7_expm<<<NB,1024,0,stream>>>(Ag, Al, mask, gains, scal, Mfin);
  k8_cmat<<<dim3(8,NB),256,0,stream>>>(Mfin, obasis, Cb);
  k9_out<<<dim3(16,8,NB),256,0,stream>>>(proj, Cb, out);
}

// Round 2
// 612.177 us; speedup vs baseline: 1.1757x; 1.1757x over previous
//
#include <hip/hip_runtime.h>
#include <math.h>

#define NB 32
#define NN 1024
#define ND 1024
#define NO 1024
#define NH 512
#define NR 64

// ---------------- workspace offsets (in floats) ----------------
// NOTE: colsum partials (32*16*1024 = 524288) alias OFF_PG: k0/k1 finish
// before the wg GEMM writes pg_ (stream-ordered), sizes match exactly.
// k2's G-partial (32768) also aliases OFF_PG (after k1, before wg GEMM).
// k2's proj-partial (2097152) aliases OFF_C (Cb written later by k8).
#define OFF_PM     0u         /* 32768 */
#define OFF_PMSQ   32768u     /* 32 */
#define OFF_ROWSQ  32800u     /* 32768 */
#define OFF_G      65568u     /* 32768 */
#define OFF_H0     98336u     /* 32768 */
#define OFF_H1     131104u    /* 16384 */
#define OFF_LOCAL  147488u    /* 16384 */
#define OFF_P1     163872u    /* 131072  w1 partials (8*32*512) */
#define OFF_P2     294944u    /* 65536   w2 partials (4*32*512) */
#define OFF_PG     360480u    /* 524288  wg partials (4*32*4096)  == colsum part == Gp */
#define OFF_PL     884768u    /* 524288 */
#define OFF_AG     1409056u   /* 131072 */
#define OFF_AL     1540128u   /* 131072 */
#define OFF_MASK   1671200u   /* 2048 */
#define OFF_GAINS  1673248u   /* 2048 */
#define OFF_SCAL   1675296u   /* 128 */
#define OFF_MFIN   1675424u   /* 131072 */
#define OFF_C      1806496u   /* 2097152  Cb == projp (k2 partial) */
#define OFF_PROJ   3903648u   /* 2097152 */
#define OFF_BT     6000800u   /* 65536  basisT (1024 x 64) */
/* total 6066336 floats ~= 24.27 MB (<= proven 24.5 MB) */

// ---------------- kT: basisT[d][r] = basis[r][d]  (64x1024 -> 1024x64) ----------------
__global__ __launch_bounds__(256) void kT_basis(const float* __restrict__ basis, float* __restrict__ basisT){
  __shared__ float s[64][65];
  int d0 = blockIdx.x*64;
  int tid = threadIdx.x;
  #pragma unroll
  for(int i=0;i<16;i++){
    int idx = i*256 + tid;          // 0..4095
    int r = idx>>6, dl = idx&63;
    s[r][dl] = basis[(size_t)r*ND + d0 + dl];
  }
  __syncthreads();
  #pragma unroll
  for(int i=0;i<16;i++){
    int idx = i*256 + tid;
    int dl = idx>>6, r = idx&63;
    basisT[(size_t)(d0+dl)*64 + r] = s[r][dl];
  }
}

// ---------------- K0: column sums of pt = x[:,1:,:] + rowsq (float4, 16 n-segments) ----------------
__global__ __launch_bounds__(256) void k0_colsum(const float* __restrict__ x, float* __restrict__ part,
    float* __restrict__ rowsq){
  __shared__ float red[4][64];
  int tid = threadIdx.x;
  int nseg = blockIdx.x, b = blockIdx.y;
  int d4 = tid*4;
  int lane = tid & 63, wv = tid >> 6;
  const float* xp = x + (size_t)b*NN*ND + d4;
  int nstart = nseg*64; if(nseg==0) nstart = 1;
  int nend = nseg*64 + 64;
  float sx=0.f, sy=0.f, sz=0.f, sw=0.f;
  #pragma unroll 4
  for(int n=nstart; n<nend; n++){
    float4 v = *(const float4*)&xp[(size_t)n*ND];
    sx+=v.x; sy+=v.y; sz+=v.z; sw+=v.w;
    float s = v.x*v.x + v.y*v.y + v.z*v.z + v.w*v.w;
    #pragma unroll
    for(int o=32;o>0;o>>=1) s += __shfl_down(s, o);
    if(lane==0) red[wv][n - nseg*64] = s;
  }
  *(float4*)&part[(size_t)(b*16+nseg)*1024 + d4] = make_float4(sx,sy,sz,sw);
  __syncthreads();
  if(tid < 64 && !(nseg==0 && tid==0)){
    rowsq[b*1024 + nseg*64 + tid] = red[0][tid]+red[1][tid]+red[2][tid]+red[3][tid];
  }
}

// ---------------- K1: pm = colsum/1023, pmsq[b] = sum(pm^2)/D ----------------
__global__ __launch_bounds__(256) void k1_pmreduce(const float* __restrict__ part, float* __restrict__ pm, float* __restrict__ pmsq){
  __shared__ float red[256];
  int b = blockIdx.x, tid = threadIdx.x;
  float acc = 0.f;
  #pragma unroll
  for(int i=0;i<4;i++){
    int d = i*256 + tid;
    float s = 0.f;
    #pragma unroll
    for(int ks=0;ks<16;ks++) s += part[(size_t)(b*16+ks)*1024 + d];
    float p = s * (1.0f/1023.0f);
    pm[b*1024+d] = p;
    acc += p*p;
  }
  red[tid] = acc; __syncthreads();
  for(int o=128;o>0;o>>=1){ if(tid<o) red[tid]+=red[tid+o]; __syncthreads(); }
  if(tid==0) pmsq[b] = red[0]*(1.0f/1024.0f);
}

// ---------------- K2: LDS-tiled GEMM proj = x @ basisT, k-split x2; G = x.pm partials ----------------
// 64 rows x 64 cols per block, 256 threads (4x4 per thread), 8 k-chunks of 64 per half.
// xs stored transposed [k][row] with XOR swizzle on row bits 2-3 (2-way banks = free).
// bs staged as straight float4 copy from bT (no transpose stores).
__global__ __launch_bounds__(256) void k2_proj(const float* __restrict__ x, const float* __restrict__ bT,
    const float* __restrict__ pm, float* __restrict__ proj, float* __restrict__ projp,
    float* __restrict__ G, float* __restrict__ Gp){
  __shared__ __align__(16) float xs[64][68];
  __shared__ __align__(16) float bs[64][68];
  int tid = threadIdx.x;
  int row0 = blockIdx.x*64;
  int b = row0 >> 10;
  int kh = blockIdx.y;               // k-half: 0 or 1
  int kbase = kh*512;
  int lrow = tid>>4, lkv = tid&15;   // staging map
  int rg = tid>>4, cg = tid&15;      // compute map
  float acc[4][4];
  #pragma unroll
  for(int i_=0;i_<4;i_++){ acc[i_][0]=0.f; acc[i_][1]=0.f; acc[i_][2]=0.f; acc[i_][3]=0.f; }
  float gp[4]={0.f,0.f,0.f,0.f};
  int sw = ((lkv>>1)&3)<<2;          // store swizzle: ((k>>3)&3)<<2 with k=4*lkv+c
  for(int kc=0;kc<8;kc++){
    int k0 = kbase + kc*64;
    float4 p4 = *(const float4*)&pm[(size_t)b*ND + k0 + lkv*4];
    #pragma unroll
    for(int i=0;i<4;i++){
      int r = lrow + 16*i;
      float4 v = *(const float4*)&x[((size_t)(row0+r))*ND + k0 + lkv*4];
      int rs = r ^ sw;
      xs[lkv*4+0][rs]=v.x; xs[lkv*4+1][rs]=v.y; xs[lkv*4+2][rs]=v.z; xs[lkv*4+3][rs]=v.w;
      gp[i] += v.x*p4.x + v.y*p4.y + v.z*p4.z + v.w*p4.w;
    }
    #pragma unroll
    for(int i=0;i<4;i++){
      int idx = tid + 256*i;         // 0..1023 float4s
      int kk = idx>>4, kv = idx&15;
      *(float4*)&bs[kk][kv*4] = *(const float4*)&bT[((size_t)(k0+kk))*64 + kv*4];
    }
    __syncthreads();
    #pragma unroll 8
    for(int kk=0;kk<64;kk++){
      float4 a = *(const float4*)&xs[kk][ (rg ^ ((kk>>3)&3)) << 2 ];
      float4 bb= *(const float4*)&bs[kk][cg*4];
      float ar[4]={a.x,a.y,a.z,a.w};
      float br[4]={bb.x,bb.y,bb.z,bb.w};
      #pragma unroll
      for(int i_=0;i_<4;i_++){
        #pragma unroll
        for(int j_=0;j_<4;j_++) acc[i_][j_] += ar[i_]*br[j_];
      }
    }
    __syncthreads();
  }
  float* dst = kh ? projp : proj;
  #pragma unroll
  for(int i_=0;i_<4;i_++){
    float4 v = make_float4(acc[i_][0],acc[i_][1],acc[i_][2],acc[i_][3]);
    *(float4*)&dst[((size_t)(row0 + rg*4 + i_))*NR + cg*4] = v;
  }
  // G partial: reduce gp across the 16 k-slices (lkv)
  #pragma unroll
  for(int i=0;i<4;i++){ int r = lrow+16*i; bs[r][lkv]=gp[i]; }
  __syncthreads();
  if(tid<64){
    float g=0.f;
    #pragma unroll
    for(int c=0;c<16;c++) g += bs[tid][c];
    if(kh) Gp[row0+tid] = g; else G[row0+tid] = g;
  }
}

// ---------------- K2R: proj += projp ----------------
__global__ __launch_bounds__(256) void k2_red(float* __restrict__ proj, const float* __restrict__ projp){
  int id = blockIdx.x*256 + threadIdx.x;   // 524288 float4s
  float4 a = *(const float4*)&proj[(size_t)id*4];
  float4 p = *(const float4*)&projp[(size_t)id*4];
  a.x+=p.x; a.y+=p.y; a.z+=p.z; a.w+=p.w;
  *(float4*)&proj[(size_t)id*4] = a;
}

// ---------------- K3: scores, top-4, detail, LayerNorm -> h0 ----------------
__global__ __launch_bounds__(256) void k3_detail(const float* __restrict__ x, const float* __restrict__ rowsq,
    const float* __restrict__ G, const float* __restrict__ Gp, const float* __restrict__ pmsq,
    const float* __restrict__ gamma_, const float* __restrict__ beta_, float* __restrict__ h0){
  __shared__ float sc[1024];
  __shared__ float rv[256];
  __shared__ int ri[256];
  __shared__ int topi[4];
  __shared__ float mred[256];
  int b = blockIdx.x, tid = threadIdx.x;
  float ps = pmsq[b];
  const float invD = 1.0f/1024.0f;
  for(int n=tid;n<1024;n+=256)
    sc[n] = (n==0) ? -INFINITY : (rowsq[b*1024+n] - 2.0f*(G[b*1024+n]+Gp[b*1024+n]))*invD + ps;
  __syncthreads();
  for(int t=0;t<4;t++){
    float bv = -INFINITY; int bi = 0x7fffffff;
    for(int n=tid;n<1024;n+=256){
      float v = sc[n];
      if(v>bv || (v==bv && n<bi)){ bv=v; bi=n; }
    }
    rv[tid]=bv; ri[tid]=bi;
    __syncthreads();
    for(int o=128;o>0;o>>=1){
      if(tid<o){
        float v=rv[tid+o]; int ii=ri[tid+o];
        if(v>rv[tid] || (v==rv[tid] && ii<ri[tid])){ rv[tid]=v; ri[tid]=ii; }
      }
      __syncthreads();
    }
    if(tid==0){ topi[t]=ri[0]; sc[ri[0]] = -INFINITY; }
    __syncthreads();
  }
  int i0=topi[0], i1=topi[1], i2=topi[2], i3=topi[3];
  float dv[4]; float dsum=0.f;
  #pragma unroll
  for(int jj=0;jj<4;jj++){
    int d = tid + jj*256;
    float v = 0.25f*(x[((size_t)(b*NN+i0))*ND+d] + x[((size_t)(b*NN+i1))*ND+d]
                   + x[((size_t)(b*NN+i2))*ND+d] + x[((size_t)(b*NN+i3))*ND+d]);
    dv[jj]=v; dsum+=v;
  }
  mred[tid]=dsum; __syncthreads();
  for(int o=128;o>0;o>>=1){ if(tid<o) mred[tid]+=mred[tid+o]; __syncthreads(); }
  float mu = mred[0]*invD;
  __syncthreads();
  float vs=0.f;
  #pragma unroll
  for(int jj=0;jj<4;jj++){ float t2=dv[jj]-mu; vs+=t2*t2; }
  mred[tid]=vs; __syncthreads();
  for(int o=128;o>0;o>>=1){ if(tid<o) mred[tid]+=mred[tid+o]; __syncthreads(); }
  float var = mred[0]*invD;
  float rstd = rsqrtf(var + 1e-5f);
  #pragma unroll
  for(int jj=0;jj<4;jj++){
    int d = tid + jj*256;
    h0[b*1024+d] = (dv[jj]-mu)*rstd*gamma_[d] + beta_[d];
  }
}

// ---------------- generic small GEMM (32 x Kd) @ (Kd x Ncols), k-split partials ----------------
__global__ __launch_bounds__(256) void gemm32_partial(const float* __restrict__ V, const float* __restrict__ W,
      float* __restrict__ part, int Kd, int Ncols){
  __shared__ __align__(16) float Vs[128][36];
  int col = blockIdx.x*256 + threadIdx.x;
  int k0 = blockIdx.y*128;
  for(int i=threadIdx.x; i<4096; i+=256){ int r=i>>7, k=i&127; Vs[k][r] = V[(size_t)r*Kd + k0 + k]; }
  __syncthreads();
  float acc[32];
  #pragma unroll
  for(int r=0;r<32;r++) acc[r]=0.f;
  #pragma unroll 4
  for(int k=0;k<128;k++){
    float wv = W[(size_t)(k0+k)*Ncols + col];
    #pragma unroll
    for(int r4=0;r4<8;r4++){
      float4 v = *(const float4*)&Vs[k][r4*4];
      acc[r4*4+0]+=v.x*wv; acc[r4*4+1]+=v.y*wv; acc[r4*4+2]+=v.z*wv; acc[r4*4+3]+=v.w*wv;
    }
  }
  #pragma unroll
  for(int r=0;r<32;r++) part[((size_t)(blockIdx.y*32 + r))*Ncols + col] = acc[r];
}

// ---------------- reductions of partials ----------------
__global__ __launch_bounds__(256) void k_red_gelu(const float* __restrict__ part, const float* __restrict__ b1, float* __restrict__ h1){
  int id = blockIdx.x*256 + threadIdx.x;  // 16384
  int b_ = id >> 9, j = id & 511;
  float s = b1[j];
  #pragma unroll
  for(int ks=0;ks<8;ks++) s += part[(size_t)(ks*32+b_)*512 + j];
  h1[id] = 0.5f*s*(1.0f + erff(s*0.70710678118654752440f));
}
__global__ __launch_bounds__(256) void k_red_local(const float* __restrict__ part, const float* __restrict__ b2, float* __restrict__ lcl){
  int id = blockIdx.x*256 + threadIdx.x;  // 16384
  int b_ = id >> 9, j = id & 511;
  float s = b2[j];
  #pragma unroll
  for(int ks=0;ks<4;ks++) s += part[(size_t)(ks*32+b_)*512 + j];
  lcl[id] = s;
}
__global__ __launch_bounds__(256) void k_red_gl(const float* __restrict__ pg, const float* __restrict__ pl,
    const float* __restrict__ bg, const float* __restrict__ bl, float* __restrict__ Ag, float* __restrict__ Al){
  int id = blockIdx.x*256 + threadIdx.x;  // 131072
  int c = id & 4095;
  int b_ = id >> 12;
  float sg = bg[c], sl = bl[c];
  #pragma unroll
  for(int ks=0;ks<4;ks++){
    sg += pg[(size_t)(ks*32 + b_)*4096 + c];
    sl += pl[(size_t)(ks*32 + b_)*4096 + c];
  }
  Ag[id] = sg; Al[id] = sl;
}

// ---------------- heads: mode_mask, gains, alpha/beta/gate ----------------
__global__ __launch_bounds__(1024) void k_heads(const float* __restrict__ context, const float* __restrict__ lcl,
    const float* __restrict__ wm, const float* __restrict__ bm,
    const float* __restrict__ wgain, const float* __restrict__ bgain,
    const float* __restrict__ wgate, const float* __restrict__ bgate,
    const float* __restrict__ wa, const float* __restrict__ ba,
    const float* __restrict__ wb, const float* __restrict__ bb,
    float* __restrict__ mask, float* __restrict__ gains, float* __restrict__ scal){
  __shared__ float fs[1024];
  __shared__ float redm[16][64];
  __shared__ float redg[16][64];
  __shared__ float wra[16], wrb[16], wrg[16];
  int b = blockIdx.x, tid = threadIdx.x;
  fs[tid] = (tid < 512) ? context[b*512 + tid] : lcl[b*512 + tid - 512];
  __syncthreads();
  int j = tid & 63, kq = tid >> 6;   // lane, wave
  const float* wmp = wm    + (size_t)(kq*64)*64 + j;
  const float* wgp = wgain + (size_t)(kq*64)*64 + j;
  float am = 0.f, ag = 0.f;
  #pragma unroll 8
  for(int k=0;k<64;k++){
    float f = fs[kq*64 + k];
    am += f * wmp[k*64];
    ag += f * wgp[k*64];
  }
  redm[kq][j] = am; redg[kq][j] = ag;
  float f = fs[tid];
  float pa = f*wa[tid], pb = f*wb[tid], pg = f*wgate[tid];
  #pragma unroll
  for(int o=32;o>0;o>>=1){
    pa += __shfl_down(pa, o);
    pb += __shfl_down(pb, o);
    pg += __shfl_down(pg, o);
  }
  if(j == 0){ wra[kq]=pa; wrb[kq]=pb; wrg[kq]=pg; }
  __syncthreads();
  for(int o=8;o>0;o>>=1){
    if(kq < o){ redm[kq][j] += redm[kq+o][j]; redg[kq][j] += redg[kq+o][j]; }
    __syncthreads();
  }
  if(tid < 64){
    float m = redm[0][tid] + bm[tid];
    mask[b*64+tid] = 1.0f/(1.0f+expf(-m));
    float g = redg[0][tid] + bgain[tid];
    gains[b*64+tid] = 1.0f + 0.1f*tanhf(g);
  }
  if(tid == 0){
    float sa=0.f, sb=0.f, sg=0.f;
    #pragma unroll
    for(int i=0;i<16;i++){ sa+=wra[i]; sb+=wrb[i]; sg+=wrg[i]; }
    scal[b*4+0] = 0.5f/(1.0f+expf(-(sa+ba[0])));    // alpha
    scal[b*4+1] = 0.25f*tanhf(sb+bb[0]);            // beta
    scal[b*4+2] = 1.0f/(1.0f+expf(-(sg+bgate[0]))); // gate
  }
}

// ---------------- K7: mg/ml, comm, omega, expm (scaling+squaring Taylor), Mfin ----------------
__global__ __launch_bounds__(1024) void k7_expm(const float* __restrict__ Ag, const float* __restrict__ Al,
    const float* __restrict__ mask, const float* __restrict__ gains, const float* __restrict__ scal,
    float* __restrict__ Mfin){
  __shared__ __align__(16) float B0s[64][66];
  __shared__ __align__(16) float B1s[64][66];
  __shared__ __align__(16) float B2s[64][66];
  __shared__ float msks[64];
  __shared__ float colsum[64];
  __shared__ int ssh;
  int b = blockIdx.x, tid = threadIdx.x;
  int ig = tid>>5, jg = tid&31;
  int i0 = ig*2, j0 = jg*2;
  if(tid<64) msks[tid] = mask[b*64+tid];
  __syncthreads();
  float alpha = scal[b*4+0], bta = scal[b*4+1], gate = scal[b*4+2];
  const float* ag = Ag + b*4096;
  const float* al = Al + b*4096;
  #pragma unroll
  for(int di=0;di<2;di++){
    #pragma unroll
    for(int dj=0;dj<2;dj++){
      int i=i0+di, jx=j0+dj;
      float mm_ = msks[i]*msks[jx]*0.5f;
      B0s[i][jx] = mm_*(ag[i*64+jx]-ag[jx*64+i]);   // mg
      B1s[i][jx] = mm_*(al[i*64+jx]-al[jx*64+i]);   // ml
    }
  }
  __syncthreads();
  {
    float c00=0.f,c01=0.f,c10=0.f,c11=0.f;
    #pragma unroll 4
    for(int k=0;k<64;k++){
      float a0=B1s[i0][k], a1=B1s[i0+1][k];
      float m0=B0s[i0][k], m1=B0s[i0+1][k];
      float2 u = *(const float2*)&B0s[k][j0];
      float2 w = *(const float2*)&B1s[k][j0];
      c00 += a0*u.x - m0*w.x;  c01 += a0*u.y - m0*w.y;
      c10 += a1*u.x - m1*w.x;  c11 += a1*u.y - m1*w.y;
    }
    B2s[i0][j0]=c00; B2s[i0][j0+1]=c01; B2s[i0+1][j0]=c10; B2s[i0+1][j0+1]=c11;
  }
  __syncthreads();
  const float bc = bta*(1.0f/12.0f);
  #pragma unroll
  for(int di=0;di<2;di++){
    #pragma unroll
    for(int dj=0;dj<2;dj++){
      int i=i0+di, jx=j0+dj;
      B0s[i][jx] = alpha*0.5f*(B0s[i][jx]+B1s[i][jx]) + bc*B2s[i][jx];  // omega
    }
  }
  __syncthreads();
  if(tid<64){
    float s=0.f;
    for(int i=0;i<64;i++) s += fabsf(B0s[i][tid]);
    colsum[tid]=s;
  }
  __syncthreads();
  if(tid==0){
    float m=0.f;
    for(int jx=0;jx<64;jx++) m = fmaxf(m, colsum[jx]);
    int s=0;
    while(m>0.5f && s<30){ m*=0.5f; s++; }
    ssh = s;
  }
  __syncthreads();
  int sh = ssh;
  float scl = ldexpf(1.0f, -sh);
  #pragma unroll
  for(int di=0;di<2;di++){
    #pragma unroll
    for(int dj=0;dj<2;dj++){ int i=i0+di,jx=j0+dj; B0s[i][jx]*=scl; }
  }
  __syncthreads();
  #pragma unroll
  for(int di=0;di<2;di++){
    #pragma unroll
    for(int dj=0;dj<2;dj++){
      int i=i0+di, jx=j0+dj;
      B1s[i][jx] = ((i==jx)?1.0f:0.0f) + B0s[i][jx]*0.125f;
    }
  }
  __syncthreads();
  for(int kk=7;kk>=1;kk--){
    float c00=0.f,c01=0.f,c10=0.f,c11=0.f;
    #pragma unroll 4
    for(int k=0;k<64;k++){
      float a0=B0s[i0][k], a1=B0s[i0+1][k];
      float2 u = *(const float2*)&B1s[k][j0];
      c00+=a0*u.x; c01+=a0*u.y; c10+=a1*u.x; c11+=a1*u.y;
    }
    B2s[i0][j0]=c00; B2s[i0][j0+1]=c01; B2s[i0+1][j0]=c10; B2s[i0+1][j0+1]=c11;
    __syncthreads();
    float inv = 1.0f/(float)kk;
    #pragma unroll
    for(int di=0;di<2;di++){
      #pragma unroll
      for(int dj=0;dj<2;dj++){
        int i=i0+di, jx=j0+dj;
        B1s[i][jx] = ((i==jx)?1.0f:0.0f) + B2s[i][jx]*inv;
      }
    }
    __syncthreads();
  }
  float (*Q)[66] = B1s; float (*T)[66] = B2s;
  for(int t=0;t<sh;t++){
    float c00=0.f,c01=0.f,c10=0.f,c11=0.f;
    #pragma unroll 4
    for(int k=0;k<64;k++){
      float a0=Q[i0][k], a1=Q[i0+1][k];
      float2 u = *(const float2*)&Q[k][j0];
      c00+=a0*u.x; c01+=a0*u.y; c10+=a1*u.x; c11+=a1*u.y;
    }
    T[i0][j0]=c00; T[i0][j0+1]=c01; T[i0+1][j0]=c10; T[i0+1][j0+1]=c11;
    __syncthreads();
    float (*tmp)[66]=Q; Q=T; T=tmp;
  }
  float g0 = gains[b*64+j0], g1 = gains[b*64+j0+1];
  float* mf = Mfin + b*4096;
  #pragma unroll
  for(int di=0;di<2;di++){
    int i=i0+di;
    float2 v;
    v.x = gate*(Q[i][j0]*g0   - ((i==j0)?1.0f:0.0f));
    v.y = gate*(Q[i][j0+1]*g1 - ((i==j0+1)?1.0f:0.0f));
    *(float2*)&mf[i*64+j0] = v;
  }
}

// ---------------- K8: C_b = Mfin_b @ output_basis ----------------
__global__ __launch_bounds__(256) void k8_cmat(const float* __restrict__ Mfin, const float* __restrict__ ob, float* __restrict__ C){
  __shared__ __align__(16) float MT[64][68];
  int b = blockIdx.y; int o0 = blockIdx.x*128;
  int tid = threadIdx.x;
  for(int idx=tid; idx<4096; idx+=256){ int i=idx>>6, k=idx&63; MT[k][i] = Mfin[b*4096+idx]; }
  __syncthreads();
  int cg = tid&31, rg = tid>>5;
  float acc[8][4];
  #pragma unroll
  for(int r=0;r<8;r++){ acc[r][0]=0.f; acc[r][1]=0.f; acc[r][2]=0.f; acc[r][3]=0.f; }
  for(int k=0;k<64;k++){
    float4 bv = *(const float4*)&ob[(size_t)k*NO + o0 + cg*4];
    float4 a0 = *(const float4*)&MT[k][rg*8];
    float4 a1 = *(const float4*)&MT[k][rg*8+4];
    float arr[8]={a0.x,a0.y,a0.z,a0.w,a1.x,a1.y,a1.z,a1.w};
    #pragma unroll
    for(int r=0;r<8;r++){
      acc[r][0]+=arr[r]*bv.x; acc[r][1]+=arr[r]*bv.y; acc[r][2]+=arr[r]*bv.z; acc[r][3]+=arr[r]*bv.w;
    }
  }
  #pragma unroll
  for(int r=0;r<8;r++){
    *(float4*)&C[((size_t)(b*64 + rg*8+r))*NO + o0 + cg*4] = make_float4(acc[r][0],acc[r][1],acc[r][2],acc[r][3]);
  }
}

// ---------------- K9: out_b = proj_b @ C_b ----------------
__global__ __launch_bounds__(256) void k9_out(const float* __restrict__ proj, const float* __restrict__ C, float* __restrict__ out){
  __shared__ __align__(16) float PT[64][132];
  __shared__ __align__(16) float CS[64][68];
  int b = blockIdx.z; int row0 = blockIdx.y*128; int o0 = blockIdx.x*64;
  int tid = threadIdx.x;
  #pragma unroll
  for(int i=0;i<8;i++){
    int f = tid + 256*i; int r = f>>4; int kv = f&15;
    float4 v = *(const float4*)&proj[((size_t)(b*NN + row0 + r))*NR + kv*4];
    PT[kv*4+0][r]=v.x; PT[kv*4+1][r]=v.y; PT[kv*4+2][r]=v.z; PT[kv*4+3][r]=v.w;
  }
  #pragma unroll
  for(int i=0;i<4;i++){
    int f = tid + 256*i; int k = f>>4; int kv = f&15;
    *(float4*)&CS[k][kv*4] = *(const float4*)&C[((size_t)(b*NR + k))*NO + o0 + kv*4];
  }
  __syncthreads();
  int rg = tid>>4, cg = tid&15;
  float acc[8][4];
  #pragma unroll
  for(int r=0;r<8;r++){ acc[r][0]=0.f; acc[r][1]=0.f; acc[r][2]=0.f; acc[r][3]=0.f; }
  #pragma unroll 8
  for(int k=0;k<64;k++){
    float4 bv = *(const float4*)&CS[k][cg*4];
    float4 a0 = *(const float4*)&PT[k][rg*8];
    float4 a1 = *(const float4*)&PT[k][rg*8+4];
    float arr[8]={a0.x,a0.y,a0.z,a0.w,a1.x,a1.y,a1.z,a1.w};
    #pragma unroll
    for(int r=0;r<8;r++){
      acc[r][0]+=arr[r]*bv.x; acc[r][1]+=arr[r]*bv.y; acc[r][2]+=arr[r]*bv.z; acc[r][3]+=arr[r]*bv.w;
    }
  }
  #pragma unroll
  for(int r=0;r<8;r++){
    *(float4*)&out[((size_t)(b*NN + row0 + rg*8 + r))*NO + o0 + cg*4] =
        make_float4(acc[r][0],acc[r][1],acc[r][2],acc[r][3]);
  }
}

extern "C" void kernel_launch(void* const* d_in, const int* in_sizes, int n_in,
                              void* d_out, int out_size, void* d_ws, size_t ws_size,
                              hipStream_t stream) {
  (void)in_sizes; (void)n_in; (void)out_size; (void)ws_size;
  const float* x       = (const float*)d_in[0];
  const float* context = (const float*)d_in[1];
  const float* ibasis  = (const float*)d_in[2];
  const float* obasis  = (const float*)d_in[3];
  const float* lng     = (const float*)d_in[4];
  const float* lnb     = (const float*)d_in[5];
  const float* w1      = (const float*)d_in[6];
  const float* b1      = (const float*)d_in[7];
  const float* w2      = (const float*)d_in[8];
  const float* b2      = (const float*)d_in[9];
  const float* wg      = (const float*)d_in[10];
  const float* bg      = (const float*)d_in[11];
  const float* wl      = (const float*)d_in[12];
  const float* bl      = (const float*)d_in[13];
  const float* wm      = (const float*)d_in[14];
  const float* bm      = (const float*)d_in[15];
  const float* wgain   = (const float*)d_in[16];
  const float* bgain   = (const float*)d_in[17];
  const float* wgate   = (const float*)d_in[18];
  const float* bgate   = (const float*)d_in[19];
  const float* wa      = (const float*)d_in[20];
  const float* ba      = (const float*)d_in[21];
  const float* wb      = (const float*)d_in[22];
  const float* bb      = (const float*)d_in[23];
  float* out = (float*)d_out;
  float* ws  = (float*)d_ws;

  float* pm    = ws + OFF_PM;
  float* pmsq  = ws + OFF_PMSQ;
  float* rowsq = ws + OFF_ROWSQ;
  float* G     = ws + OFF_G;
  float* h0    = ws + OFF_H0;
  float* h1    = ws + OFF_H1;
  float* lcl   = ws + OFF_LOCAL;
  float* p1    = ws + OFF_P1;
  float* p2    = ws + OFF_P2;
  float* pg_   = ws + OFF_PG;
  float* part  = ws + OFF_PG;   // alias: consumed by k1 before Gp/pg_ writes
  float* Gp    = ws + OFF_PG;   // alias: written by k2 after k1, read by k3 before wg GEMM
  float* pl_   = ws + OFF_PL;
  float* Ag    = ws + OFF_AG;
  float* Al    = ws + OFF_AL;
  float* mask  = ws + OFF_MASK;
  float* gains = ws + OFF_GAINS;
  float* scal  = ws + OFF_SCAL;
  float* Mfin  = ws + OFF_MFIN;
  float* Cb    = ws + OFF_C;
  float* projp = ws + OFF_C;    // alias: consumed by k2_red before k8 writes Cb
  float* proj  = ws + OFF_PROJ;
  float* bT    = ws + OFF_BT;

  kT_basis<<<16,256,0,stream>>>(ibasis, bT);
  k0_colsum<<<dim3(16,NB),256,0,stream>>>(x, part, rowsq);
  k1_pmreduce<<<NB,256,0,stream>>>(part, pm, pmsq);
  k2_proj<<<dim3(512,2),256,0,stream>>>(x, bT, pm, proj, projp, G, Gp);
  k2_red<<<2048,256,0,stream>>>(proj, projp);
  k3_detail<<<NB,256,0,stream>>>(x, rowsq, G, Gp, pmsq, lng, lnb, h0);
  gemm32_partial<<<dim3(2,8),256,0,stream>>>(h0, w1, p1, 1024, 512);
  k_red_gelu<<<64,256,0,stream>>>(p1, b1, h1);
  gemm32_partial<<<dim3(2,4),256,0,stream>>>(h1, w2, p2, 512, 512);
  k_red_local<<<64,256,0,stream>>>(p2, b2, lcl);
  gemm32_partial<<<dim3(16,4),256,0,stream>>>(context, wg, pg_, 512, 4096);
  gemm32_partial<<<dim3(16,4),256,0,stream>>>(lcl, wl, pl_, 512, 4096);
  k_red_gl<<<512,256,0,stream>>>(pg_, pl_, bg, bl, Ag, Al);
  k_heads<<<NB,1024,0,stream>>>(context, lcl, wm, bm, wgain, bgain, wgate, bgate, wa, ba, wb, bb, mask, gains, scal);
  k7_expm<<<NB,1024,0,stream>>>(Ag, Al, mask, gains, scal, Mfin);
  k8_cmat<<<dim3(8,NB),256,0,stream>>>(Mfin, obasis, Cb);
  k9_out<<<dim3(16,8,NB),256,0,stream>>>(proj, Cb, out);
}

// Round 3
// 580.589 us; speedup vs baseline: 1.2397x; 1.0544x over previous
//
#include <hip/hip_runtime.h>
#include <math.h>

#define NB 32
#define NN 1024
#define ND 1024
#define NO 1024
#define NH 512
#define NR 64

// ---------------- workspace offsets (in floats) ----------------
// NOTE: colsum partials (32*16*1024 = 524288) alias OFF_PG: k0/k1 finish
// before the wg GEMM writes pg_ (stream-ordered), sizes match exactly.
// k2's G-partial (32768) also aliases OFF_PG (after k1, before wg GEMM; k3
// consumes it before gemm32_gl writes pg_).
// k2's proj-partial (2097152) aliases OFF_C (Cb written later by k8).
#define OFF_PM     0u         /* 32768 */
#define OFF_PMSQ   32768u     /* 32 */
#define OFF_ROWSQ  32800u     /* 32768 */
#define OFF_G      65568u     /* 32768 */
#define OFF_H0     98336u     /* 32768 */
#define OFF_H1     131104u    /* 16384 */
#define OFF_LOCAL  147488u    /* 16384 */
#define OFF_P1     163872u    /* 131072  w1 partials (8*32*512) */
#define OFF_P2     294944u    /* 65536   w2 partials (4*32*512) */
#define OFF_PG     360480u    /* 524288  wg partials (4*32*4096)  == colsum part == Gp */
#define OFF_PL     884768u    /* 524288 */
#define OFF_MFIN   1675424u   /* 131072 */
#define OFF_C      1806496u   /* 2097152  Cb == projp (k2 partial) */
#define OFF_PROJ   3903648u   /* 2097152 */
#define OFF_BT     6000800u   /* 65536  basisT (1024 x 64) */
/* total 6066336 floats ~= 24.27 MB (<= proven 24.5 MB) */

// compile-time float4 component select (k must be a literal under full unroll)
#define AK(av,k) ((k&3)==0?av[(k)>>2].x:((k&3)==1?av[(k)>>2].y:((k&3)==2?av[(k)>>2].z:av[(k)>>2].w)))

// ---------------- kT: basisT[d][r] = basis[r][d]  (64x1024 -> 1024x64) ----------------
__global__ __launch_bounds__(256) void kT_basis(const float* __restrict__ basis, float* __restrict__ basisT){
  __shared__ float s[64][65];
  int d0 = blockIdx.x*64;
  int tid = threadIdx.x;
  #pragma unroll
  for(int i=0;i<16;i++){
    int idx = i*256 + tid;          // 0..4095
    int r = idx>>6, dl = idx&63;
    s[r][dl] = basis[(size_t)r*ND + d0 + dl];
  }
  __syncthreads();
  #pragma unroll
  for(int i=0;i<16;i++){
    int idx = i*256 + tid;
    int dl = idx>>6, r = idx&63;
    basisT[(size_t)(d0+dl)*64 + r] = s[r][dl];
  }
}

// ---------------- K0: column sums of pt = x[:,1:,:] + rowsq ----------------
__global__ __launch_bounds__(256) void k0_colsum(const float* __restrict__ x, float* __restrict__ part,
    float* __restrict__ rowsq){
  __shared__ float red[4][64];
  int tid = threadIdx.x;
  int nseg = blockIdx.x, b = blockIdx.y;
  int d4 = tid*4;
  int lane = tid & 63, wv = tid >> 6;
  const float* xp = x + (size_t)b*NN*ND + d4;
  int nstart = nseg*64; if(nseg==0) nstart = 1;
  int nend = nseg*64 + 64;
  float sx=0.f, sy=0.f, sz=0.f, sw=0.f;
  #pragma unroll 4
  for(int n=nstart; n<nend; n++){
    float4 v = *(const float4*)&xp[(size_t)n*ND];
    sx+=v.x; sy+=v.y; sz+=v.z; sw+=v.w;
    float s = v.x*v.x + v.y*v.y + v.z*v.z + v.w*v.w;
    #pragma unroll
    for(int o=32;o>0;o>>=1) s += __shfl_down(s, o);
    if(lane==0) red[wv][n - nseg*64] = s;
  }
  *(float4*)&part[(size_t)(b*16+nseg)*1024 + d4] = make_float4(sx,sy,sz,sw);
  __syncthreads();
  if(tid < 64 && !(nseg==0 && tid==0)){
    rowsq[b*1024 + nseg*64 + tid] = red[0][tid]+red[1][tid]+red[2][tid]+red[3][tid];
  }
}

// ---------------- K1: pm = colsum/1023, pmsq[b] = sum(pm^2)/D ----------------
__global__ __launch_bounds__(256) void k1_pmreduce(const float* __restrict__ part, float* __restrict__ pm, float* __restrict__ pmsq){
  __shared__ float red[256];
  int b = blockIdx.x, tid = threadIdx.x;
  float acc = 0.f;
  #pragma unroll
  for(int i=0;i<4;i++){
    int d = i*256 + tid;
    float s = 0.f;
    #pragma unroll
    for(int ks=0;ks<16;ks++) s += part[(size_t)(b*16+ks)*1024 + d];
    float p = s * (1.0f/1023.0f);
    pm[b*1024+d] = p;
    acc += p*p;
  }
  red[tid] = acc; __syncthreads();
  for(int o=128;o>0;o>>=1){ if(tid<o) red[tid]+=red[tid+o]; __syncthreads(); }
  if(tid==0) pmsq[b] = red[0]*(1.0f/1024.0f);
}

// ---------------- K2: LDS-tiled GEMM proj = x @ basisT, k-split x2; G = x.pm partials ----------------
__global__ __launch_bounds__(256) void k2_proj(const float* __restrict__ x, const float* __restrict__ bT,
    const float* __restrict__ pm, float* __restrict__ proj, float* __restrict__ projp,
    float* __restrict__ G, float* __restrict__ Gp){
  __shared__ __align__(16) float xs[64][68];
  __shared__ __align__(16) float bs[64][68];
  int tid = threadIdx.x;
  int row0 = blockIdx.x*64;
  int b = row0 >> 10;
  int kh = blockIdx.y;               // k-half: 0 or 1
  int kbase = kh*512;
  int lrow = tid>>4, lkv = tid&15;   // staging map
  int rg = tid>>4, cg = tid&15;      // compute map
  float acc[4][4];
  #pragma unroll
  for(int i_=0;i_<4;i_++){ acc[i_][0]=0.f; acc[i_][1]=0.f; acc[i_][2]=0.f; acc[i_][3]=0.f; }
  float gp[4]={0.f,0.f,0.f,0.f};
  int sw = ((lkv>>1)&3)<<2;          // store swizzle: ((k>>3)&3)<<2 with k=4*lkv+c
  for(int kc=0;kc<8;kc++){
    int k0 = kbase + kc*64;
    float4 p4 = *(const float4*)&pm[(size_t)b*ND + k0 + lkv*4];
    #pragma unroll
    for(int i=0;i<4;i++){
      int r = lrow + 16*i;
      float4 v = *(const float4*)&x[((size_t)(row0+r))*ND + k0 + lkv*4];
      int rs = r ^ sw;
      xs[lkv*4+0][rs]=v.x; xs[lkv*4+1][rs]=v.y; xs[lkv*4+2][rs]=v.z; xs[lkv*4+3][rs]=v.w;
      gp[i] += v.x*p4.x + v.y*p4.y + v.z*p4.z + v.w*p4.w;
    }
    #pragma unroll
    for(int i=0;i<4;i++){
      int idx = tid + 256*i;         // 0..1023 float4s
      int kk = idx>>4, kv = idx&15;
      *(float4*)&bs[kk][kv*4] = *(const float4*)&bT[((size_t)(k0+kk))*64 + kv*4];
    }
    __syncthreads();
    #pragma unroll 8
    for(int kk=0;kk<64;kk++){
      float4 a = *(const float4*)&xs[kk][ (rg ^ ((kk>>3)&3)) << 2 ];
      float4 bb= *(const float4*)&bs[kk][cg*4];
      float ar[4]={a.x,a.y,a.z,a.w};
      float br[4]={bb.x,bb.y,bb.z,bb.w};
      #pragma unroll
      for(int i_=0;i_<4;i_++){
        #pragma unroll
        for(int j_=0;j_<4;j_++) acc[i_][j_] += ar[i_]*br[j_];
      }
    }
    __syncthreads();
  }
  float* dst = kh ? projp : proj;
  #pragma unroll
  for(int i_=0;i_<4;i_++){
    float4 v = make_float4(acc[i_][0],acc[i_][1],acc[i_][2],acc[i_][3]);
    *(float4*)&dst[((size_t)(row0 + rg*4 + i_))*NR + cg*4] = v;
  }
  __syncthreads();
  #pragma unroll
  for(int i=0;i<4;i++){ int r = lrow+16*i; bs[r][lkv]=gp[i]; }
  __syncthreads();
  if(tid<64){
    float g=0.f;
    #pragma unroll
    for(int c=0;c<16;c++) g += bs[tid][c];
    if(kh) Gp[row0+tid] = g; else G[row0+tid] = g;
  }
}

// ---------------- K2R: proj += projp ----------------
__global__ __launch_bounds__(256) void k2_red(float* __restrict__ proj, const float* __restrict__ projp){
  int id = blockIdx.x*256 + threadIdx.x;   // 524288 float4s
  float4 a = *(const float4*)&proj[(size_t)id*4];
  float4 p = *(const float4*)&projp[(size_t)id*4];
  a.x+=p.x; a.y+=p.y; a.z+=p.z; a.w+=p.w;
  *(float4*)&proj[(size_t)id*4] = a;
}

// ---------------- K3: scores, top-4, detail, LayerNorm -> h0 ----------------
__global__ __launch_bounds__(256) void k3_detail(const float* __restrict__ x, const float* __restrict__ rowsq,
    const float* __restrict__ G, const float* __restrict__ Gp, const float* __restrict__ pmsq,
    const float* __restrict__ gamma_, const float* __restrict__ beta_, float* __restrict__ h0){
  __shared__ float sc[1024];
  __shared__ float rv[256];
  __shared__ int ri[256];
  __shared__ int topi[4];
  __shared__ float mred[256];
  int b = blockIdx.x, tid = threadIdx.x;
  float ps = pmsq[b];
  const float invD = 1.0f/1024.0f;
  for(int n=tid;n<1024;n+=256)
    sc[n] = (n==0) ? -INFINITY : (rowsq[b*1024+n] - 2.0f*(G[b*1024+n]+Gp[b*1024+n]))*invD + ps;
  __syncthreads();
  for(int t=0;t<4;t++){
    float bv = -INFINITY; int bi = 0x7fffffff;
    for(int n=tid;n<1024;n+=256){
      float v = sc[n];
      if(v>bv || (v==bv && n<bi)){ bv=v; bi=n; }
    }
    rv[tid]=bv; ri[tid]=bi;
    __syncthreads();
    for(int o=128;o>0;o>>=1){
      if(tid<o){
        float v=rv[tid+o]; int ii=ri[tid+o];
        if(v>rv[tid] || (v==rv[tid] && ii<ri[tid])){ rv[tid]=v; ri[tid]=ii; }
      }
      __syncthreads();
    }
    if(tid==0){ topi[t]=ri[0]; sc[ri[0]] = -INFINITY; }
    __syncthreads();
  }
  int i0=topi[0], i1=topi[1], i2=topi[2], i3=topi[3];
  float dv[4]; float dsum=0.f;
  #pragma unroll
  for(int jj=0;jj<4;jj++){
    int d = tid + jj*256;
    float v = 0.25f*(x[((size_t)(b*NN+i0))*ND+d] + x[((size_t)(b*NN+i1))*ND+d]
                   + x[((size_t)(b*NN+i2))*ND+d] + x[((size_t)(b*NN+i3))*ND+d]);
    dv[jj]=v; dsum+=v;
  }
  mred[tid]=dsum; __syncthreads();
  for(int o=128;o>0;o>>=1){ if(tid<o) mred[tid]+=mred[tid+o]; __syncthreads(); }
  float mu = mred[0]*invD;
  __syncthreads();
  float vs=0.f;
  #pragma unroll
  for(int jj=0;jj<4;jj++){ float t2=dv[jj]-mu; vs+=t2*t2; }
  mred[tid]=vs; __syncthreads();
  for(int o=128;o>0;o>>=1){ if(tid<o) mred[tid]+=mred[tid+o]; __syncthreads(); }
  float var = mred[0]*invD;
  float rstd = rsqrtf(var + 1e-5f);
  #pragma unroll
  for(int jj=0;jj<4;jj++){
    int d = tid + jj*256;
    h0[b*1024+d] = (dv[jj]-mu)*rstd*gamma_[d] + beta_[d];
  }
}

// ---------------- generic small GEMM (32 x Kd) @ (Kd x Ncols), k-split partials ----------------
__global__ __launch_bounds__(256) void gemm32_partial(const float* __restrict__ V, const float* __restrict__ W,
      float* __restrict__ part, int Kd, int Ncols){
  __shared__ __align__(16) float Vs[128][36];
  int col = blockIdx.x*256 + threadIdx.x;
  int k0 = blockIdx.y*128;
  for(int i=threadIdx.x; i<4096; i+=256){ int r=i>>7, k=i&127; Vs[k][r] = V[(size_t)r*Kd + k0 + k]; }
  __syncthreads();
  float acc[32];
  #pragma unroll
  for(int r=0;r<32;r++) acc[r]=0.f;
  #pragma unroll 4
  for(int k=0;k<128;k++){
    float wv = W[(size_t)(k0+k)*Ncols + col];
    #pragma unroll
    for(int r4=0;r4<8;r4++){
      float4 v = *(const float4*)&Vs[k][r4*4];
      acc[r4*4+0]+=v.x*wv; acc[r4*4+1]+=v.y*wv; acc[r4*4+2]+=v.z*wv; acc[r4*4+3]+=v.w*wv;
    }
  }
  #pragma unroll
  for(int r=0;r<32;r++) part[((size_t)(blockIdx.y*32 + r))*Ncols + col] = acc[r];
}

// ---------------- merged wg+wl GEMM: z selects (context,wg,pg) vs (lcl,wl,pl) ----------------
__global__ __launch_bounds__(256) void gemm32_gl(const float* __restrict__ ctx, const float* __restrict__ lcl,
    const float* __restrict__ wg, const float* __restrict__ wl,
    float* __restrict__ pg, float* __restrict__ pl){
  __shared__ __align__(16) float Vs[128][36];
  const float* V = blockIdx.z ? lcl : ctx;
  const float* W = blockIdx.z ? wl : wg;
  float* part    = blockIdx.z ? pl : pg;
  int col = blockIdx.x*256 + threadIdx.x;
  int k0 = blockIdx.y*128;
  for(int i=threadIdx.x; i<4096; i+=256){ int r=i>>7, k=i&127; Vs[k][r] = V[(size_t)r*512 + k0 + k]; }
  __syncthreads();
  float acc[32];
  #pragma unroll
  for(int r=0;r<32;r++) acc[r]=0.f;
  #pragma unroll 4
  for(int k=0;k<128;k++){
    float wv = W[(size_t)(k0+k)*4096 + col];
    #pragma unroll
    for(int r4=0;r4<8;r4++){
      float4 v = *(const float4*)&Vs[k][r4*4];
      acc[r4*4+0]+=v.x*wv; acc[r4*4+1]+=v.y*wv; acc[r4*4+2]+=v.z*wv; acc[r4*4+3]+=v.w*wv;
    }
  }
  #pragma unroll
  for(int r=0;r<32;r++) part[((size_t)(blockIdx.y*32 + r))*4096 + col] = acc[r];
}

// ---------------- reductions of partials ----------------
__global__ __launch_bounds__(256) void k_red_gelu(const float* __restrict__ part, const float* __restrict__ b1, float* __restrict__ h1){
  int id = blockIdx.x*256 + threadIdx.x;  // 16384
  int b_ = id >> 9, j = id & 511;
  float s = b1[j];
  #pragma unroll
  for(int ks=0;ks<8;ks++) s += part[(size_t)(ks*32+b_)*512 + j];
  h1[id] = 0.5f*s*(1.0f + erff(s*0.70710678118654752440f));
}
__global__ __launch_bounds__(256) void k_red_local(const float* __restrict__ part, const float* __restrict__ b2, float* __restrict__ lcl){
  int id = blockIdx.x*256 + threadIdx.x;  // 16384
  int b_ = id >> 9, j = id & 511;
  float s = b2[j];
  #pragma unroll
  for(int ks=0;ks<4;ks++) s += part[(size_t)(ks*32+b_)*512 + j];
  lcl[id] = s;
}

// ---------------- K7 fused: heads + Ag/Al reduce + mg/ml/comm/omega + expm + Mfin ----------------
// 32 blocks x 1024 threads. Matmuls: thread = (row i = tid>>4, cols cg*4..cg*4+3);
// A-row cached in 16 float4 regs (constant across all 7 Horner iters), per-k one
// broadcast-friendly b128 B-read + 4 FMA. One barrier per matmul.
__global__ __launch_bounds__(1024) void k7_fused(
    const float* __restrict__ pg, const float* __restrict__ pl,
    const float* __restrict__ bg, const float* __restrict__ bl,
    const float* __restrict__ context, const float* __restrict__ lcl,
    const float* __restrict__ wm, const float* __restrict__ bm,
    const float* __restrict__ wgain, const float* __restrict__ bgain,
    const float* __restrict__ wgate, const float* __restrict__ bgate,
    const float* __restrict__ wa, const float* __restrict__ ba,
    const float* __restrict__ wb, const float* __restrict__ bb,
    float* __restrict__ Mfin){
  __shared__ __align__(16) float B0s[64][68];
  __shared__ __align__(16) float B1s[64][68];
  __shared__ __align__(16) float B2s[64][68];
  __shared__ float fs[1024];
  __shared__ float redm[16][64];
  __shared__ float redg[16][64];
  __shared__ float wra[16], wrb[16], wrg[16];
  __shared__ float msks[64], gainss[64];
  __shared__ float colsum[64];
  __shared__ float sABG[3];
  __shared__ int ssh;
  int b = blockIdx.x, tid = threadIdx.x;

  // ---- phase 1: stage raw Ag/Al (bias + 4 partials) into B0s/B1s ----
  int ig = tid>>5, jg = tid&31;
  int i0 = ig*2, j0 = jg*2;
  #pragma unroll
  for(int di=0;di<2;di++){
    #pragma unroll
    for(int dj=0;dj<2;dj++){
      int i=i0+di, jx=j0+dj, c=i*64+jx;
      float sg = bg[c], sl = bl[c];
      #pragma unroll
      for(int ks=0;ks<4;ks++){
        sg += pg[(size_t)(ks*32+b)*4096 + c];
        sl += pl[(size_t)(ks*32+b)*4096 + c];
      }
      B0s[i][jx] = sg; B1s[i][jx] = sl;
    }
  }
  // ---- phase 2: heads GEMV ----
  fs[tid] = (tid < 512) ? context[b*512 + tid] : lcl[b*512 + tid - 512];
  __syncthreads();
  int j = tid & 63, kq = tid >> 6;
  {
    const float* wmp = wm    + (size_t)(kq*64)*64 + j;
    const float* wgp = wgain + (size_t)(kq*64)*64 + j;
    float am = 0.f, ag = 0.f;
    #pragma unroll 8
    for(int k=0;k<64;k++){
      float f = fs[kq*64 + k];
      am += f * wmp[k*64];
      ag += f * wgp[k*64];
    }
    redm[kq][j] = am; redg[kq][j] = ag;
    float f = fs[tid];
    float pa = f*wa[tid], pb = f*wb[tid], pgt = f*wgate[tid];
    #pragma unroll
    for(int o=32;o>0;o>>=1){
      pa += __shfl_down(pa, o);
      pb += __shfl_down(pb, o);
      pgt += __shfl_down(pgt, o);
    }
    if(j == 0){ wra[kq]=pa; wrb[kq]=pb; wrg[kq]=pgt; }
  }
  __syncthreads();
  for(int o=8;o>0;o>>=1){
    if(kq < o){ redm[kq][j] += redm[kq+o][j]; redg[kq][j] += redg[kq+o][j]; }
    __syncthreads();
  }
  if(tid < 64){
    float m = redm[0][tid] + bm[tid];
    msks[tid] = 1.0f/(1.0f+expf(-m));
    float g = redg[0][tid] + bgain[tid];
    gainss[tid] = 1.0f + 0.1f*tanhf(g);
  }
  if(tid == 0){
    float sa=0.f, sb=0.f, sg2=0.f;
    #pragma unroll
    for(int i=0;i<16;i++){ sa+=wra[i]; sb+=wrb[i]; sg2+=wrg[i]; }
    sABG[0] = 0.5f/(1.0f+expf(-(sa+ba[0])));     // alpha
    sABG[1] = 0.25f*tanhf(sb+bb[0]);             // beta
    sABG[2] = 1.0f/(1.0f+expf(-(sg2+bgate[0]))); // gate
  }
  __syncthreads();
  float alpha = sABG[0], bta = sABG[1], gate = sABG[2];
  // ---- phase 3: mg/ml (skew * mask) via regs, write back ----
  float mgr[2][2], mlr[2][2];
  #pragma unroll
  for(int di=0;di<2;di++){
    #pragma unroll
    for(int dj=0;dj<2;dj++){
      int i=i0+di, jx=j0+dj;
      float mm_ = msks[i]*msks[jx]*0.5f;
      mgr[di][dj] = mm_*(B0s[i][jx]-B0s[jx][i]);
      mlr[di][dj] = mm_*(B1s[i][jx]-B1s[jx][i]);
    }
  }
  __syncthreads();
  #pragma unroll
  for(int di=0;di<2;di++){
    #pragma unroll
    for(int dj=0;dj<2;dj++){
      int i=i0+di, jx=j0+dj;
      B0s[i][jx] = mgr[di][dj];     // mg
      B1s[i][jx] = mlr[di][dj];     // ml
    }
  }
  __syncthreads();
  // ---- phase 4: comm = ml@mg - mg@ml (2 reg-cached passes, no inner barrier) ----
  int ir = tid>>4, cgc = tid&15;
  int jc = cgc*4;
  float4 av[16];
  {
    const float* rowp = &B1s[ir][0];           // ml row
    #pragma unroll
    for(int q=0;q<16;q++) av[q] = *(const float4*)(rowp + q*4);
    float4 t1 = make_float4(0.f,0.f,0.f,0.f);
    #pragma unroll
    for(int k=0;k<64;k++){
      float4 bv = *(const float4*)&B0s[k][jc];
      float a = AK(av,k);
      t1.x += a*bv.x; t1.y += a*bv.y; t1.z += a*bv.z; t1.w += a*bv.w;
    }
    const float* rowq = &B0s[ir][0];           // mg row
    #pragma unroll
    for(int q=0;q<16;q++) av[q] = *(const float4*)(rowq + q*4);
    float4 t2 = make_float4(0.f,0.f,0.f,0.f);
    #pragma unroll
    for(int k=0;k<64;k++){
      float4 bv = *(const float4*)&B1s[k][jc];
      float a = AK(av,k);
      t2.x += a*bv.x; t2.y += a*bv.y; t2.z += a*bv.z; t2.w += a*bv.w;
    }
    float4 cm = make_float4(t1.x-t2.x, t1.y-t2.y, t1.z-t2.z, t1.w-t2.w);
    *(float4*)&B2s[ir][jc] = cm;
  }
  __syncthreads();
  // ---- phase 5: omega in B0s (own cells, new mapping) ----
  {
    const float bc = bta*(1.0f/12.0f);
    float4 g4 = *(const float4*)&B0s[ir][jc];
    float4 l4 = *(const float4*)&B1s[ir][jc];
    float4 c4 = *(const float4*)&B2s[ir][jc];
    float4 o4;
    o4.x = alpha*0.5f*(g4.x+l4.x) + bc*c4.x;
    o4.y = alpha*0.5f*(g4.y+l4.y) + bc*c4.y;
    o4.z = alpha*0.5f*(g4.z+l4.z) + bc*c4.z;
    o4.w = alpha*0.5f*(g4.w+l4.w) + bc*c4.w;
    *(float4*)&B0s[ir][jc] = o4;
  }
  __syncthreads();
  // ---- phase 6: 1-norm -> scaling shift ----
  if(tid<64){
    float s=0.f;
    for(int i=0;i<64;i++) s += fabsf(B0s[i][tid]);
    colsum[tid]=s;
  }
  __syncthreads();
  if(tid==0){
    float m=0.f;
    for(int jx=0;jx<64;jx++) m = fmaxf(m, colsum[jx]);
    int s=0;
    while(m>0.5f && s<30){ m*=0.5f; s++; }
    ssh = s;
  }
  __syncthreads();
  int sh = ssh;
  float scl = ldexpf(1.0f, -sh);
  // ---- phase 7: scale omega + Horner init P = I + A/8 (own cells) ----
  {
    float4 a4 = *(const float4*)&B0s[ir][jc];
    a4.x*=scl; a4.y*=scl; a4.z*=scl; a4.w*=scl;
    *(float4*)&B0s[ir][jc] = a4;
    float4 p4;
    p4.x = ((ir==jc+0)?1.0f:0.0f) + a4.x*0.125f;
    p4.y = ((ir==jc+1)?1.0f:0.0f) + a4.y*0.125f;
    p4.z = ((ir==jc+2)?1.0f:0.0f) + a4.z*0.125f;
    p4.w = ((ir==jc+3)?1.0f:0.0f) + a4.w*0.125f;
    *(float4*)&B1s[ir][jc] = p4;
  }
  __syncthreads();
  // ---- phase 8: Horner, A (=scaled omega) rows cached ONCE in regs ----
  {
    const float* rowp = &B0s[ir][0];
    #pragma unroll
    for(int q=0;q<16;q++) av[q] = *(const float4*)(rowp + q*4);
  }
  float* P = &B1s[0][0];
  float* T = &B2s[0][0];
  for(int kk=7;kk>=1;kk--){
    float4 acc = make_float4(0.f,0.f,0.f,0.f);
    #pragma unroll
    for(int k=0;k<64;k++){
      float4 bv = *(const float4*)&P[(size_t)k*68 + jc];
      float a = AK(av,k);
      acc.x += a*bv.x; acc.y += a*bv.y; acc.z += a*bv.z; acc.w += a*bv.w;
    }
    float inv = 1.0f/(float)kk;
    float4 o4;
    o4.x = ((ir==jc+0)?1.0f:0.0f) + acc.x*inv;
    o4.y = ((ir==jc+1)?1.0f:0.0f) + acc.y*inv;
    o4.z = ((ir==jc+2)?1.0f:0.0f) + acc.z*inv;
    o4.w = ((ir==jc+3)?1.0f:0.0f) + acc.w*inv;
    *(float4*)&T[(size_t)ir*68 + jc] = o4;
    __syncthreads();
    float* tmp = P; P = T; T = tmp;
  }
  // ---- phase 9: squarings, Q rows reloaded each iter ----
  float* S = (P == &B1s[0][0]) ? &B2s[0][0] : &B1s[0][0];
  for(int t=0;t<sh;t++){
    #pragma unroll
    for(int q=0;q<16;q++) av[q] = *(const float4*)(P + (size_t)ir*68 + q*4);
    float4 acc = make_float4(0.f,0.f,0.f,0.f);
    #pragma unroll
    for(int k=0;k<64;k++){
      float4 bv = *(const float4*)&P[(size_t)k*68 + jc];
      float a = AK(av,k);
      acc.x += a*bv.x; acc.y += a*bv.y; acc.z += a*bv.z; acc.w += a*bv.w;
    }
    *(float4*)&S[(size_t)ir*68 + jc] = acc;
    __syncthreads();
    float* tmp = P; P = S; S = tmp;
  }
  // ---- phase 10: Mfin = gate*(Q*gains - I) ----
  {
    float4 q4 = *(const float4*)&P[(size_t)ir*68 + jc];
    float4 v;
    v.x = gate*(q4.x*gainss[jc+0] - ((ir==jc+0)?1.0f:0.0f));
    v.y = gate*(q4.y*gainss[jc+1] - ((ir==jc+1)?1.0f:0.0f));
    v.z = gate*(q4.z*gainss[jc+2] - ((ir==jc+2)?1.0f:0.0f));
    v.w = gate*(q4.w*gainss[jc+3] - ((ir==jc+3)?1.0f:0.0f));
    *(float4*)&Mfin[(size_t)b*4096 + ir*64 + jc] = v;
  }
}

// ---------------- K8: C_b = Mfin_b @ output_basis ----------------
__global__ __launch_bounds__(256) void k8_cmat(const float* __restrict__ Mfin, const float* __restrict__ ob, float* __restrict__ C){
  __shared__ __align__(16) float MT[64][68];
  int b = blockIdx.y; int o0 = blockIdx.x*128;
  int tid = threadIdx.x;
  for(int idx=tid; idx<4096; idx+=256){ int i=idx>>6, k=idx&63; MT[k][i] = Mfin[b*4096+idx]; }
  __syncthreads();
  int cg = tid&31, rg = tid>>5;
  float acc[8][4];
  #pragma unroll
  for(int r=0;r<8;r++){ acc[r][0]=0.f; acc[r][1]=0.f; acc[r][2]=0.f; acc[r][3]=0.f; }
  for(int k=0;k<64;k++){
    float4 bv = *(const float4*)&ob[(size_t)k*NO + o0 + cg*4];
    float4 a0 = *(const float4*)&MT[k][rg*8];
    float4 a1 = *(const float4*)&MT[k][rg*8+4];
    float arr[8]={a0.x,a0.y,a0.z,a0.w,a1.x,a1.y,a1.z,a1.w};
    #pragma unroll
    for(int r=0;r<8;r++){
      acc[r][0]+=arr[r]*bv.x; acc[r][1]+=arr[r]*bv.y; acc[r][2]+=arr[r]*bv.z; acc[r][3]+=arr[r]*bv.w;
    }
  }
  #pragma unroll
  for(int r=0;r<8;r++){
    *(float4*)&C[((size_t)(b*64 + rg*8+r))*NO + o0 + cg*4] = make_float4(acc[r][0],acc[r][1],acc[r][2],acc[r][3]);
  }
}

// ---------------- K9: out_b = proj_b @ C_b ----------------
__global__ __launch_bounds__(256) void k9_out(const float* __restrict__ proj, const float* __restrict__ C, float* __restrict__ out){
  __shared__ __align__(16) float PT[64][132];
  __shared__ __align__(16) float CS[64][68];
  int b = blockIdx.z; int row0 = blockIdx.y*128; int o0 = blockIdx.x*64;
  int tid = threadIdx.x;
  #pragma unroll
  for(int i=0;i<8;i++){
    int f = tid + 256*i; int r = f>>4; int kv = f&15;
    float4 v = *(const float4*)&proj[((size_t)(b*NN + row0 + r))*NR + kv*4];
    PT[kv*4+0][r]=v.x; PT[kv*4+1][r]=v.y; PT[kv*4+2][r]=v.z; PT[kv*4+3][r]=v.w;
  }
  #pragma unroll
  for(int i=0;i<4;i++){
    int f = tid + 256*i; int k = f>>4; int kv = f&15;
    *(float4*)&CS[k][kv*4] = *(const float4*)&C[((size_t)(b*NR + k))*NO + o0 + kv*4];
  }
  __syncthreads();
  int rg = tid>>4, cg = tid&15;
  float acc[8][4];
  #pragma unroll
  for(int r=0;r<8;r++){ acc[r][0]=0.f; acc[r][1]=0.f; acc[r][2]=0.f; acc[r][3]=0.f; }
  #pragma unroll 8
  for(int k=0;k<64;k++){
    float4 bv = *(const float4*)&CS[k][cg*4];
    float4 a0 = *(const float4*)&PT[k][rg*8];
    float4 a1 = *(const float4*)&PT[k][rg*8+4];
    float arr[8]={a0.x,a0.y,a0.z,a0.w,a1.x,a1.y,a1.z,a1.w};
    #pragma unroll
    for(int r=0;r<8;r++){
      acc[r][0]+=arr[r]*bv.x; acc[r][1]+=arr[r]*bv.y; acc[r][2]+=arr[r]*bv.z; acc[r][3]+=arr[r]*bv.w;
    }
  }
  #pragma unroll
  for(int r=0;r<8;r++){
    *(float4*)&out[((size_t)(b*NN + row0 + rg*8 + r))*NO + o0 + cg*4] =
        make_float4(acc[r][0],acc[r][1],acc[r][2],acc[r][3]);
  }
}

extern "C" void kernel_launch(void* const* d_in, const int* in_sizes, int n_in,
                              void* d_out, int out_size, void* d_ws, size_t ws_size,
                              hipStream_t stream) {
  (void)in_sizes; (void)n_in; (void)out_size; (void)ws_size;
  const float* x       = (const float*)d_in[0];
  const float* context = (const float*)d_in[1];
  const float* ibasis  = (const float*)d_in[2];
  const float* obasis  = (const float*)d_in[3];
  const float* lng     = (const float*)d_in[4];
  const float* lnb     = (const float*)d_in[5];
  const float* w1      = (const float*)d_in[6];
  const float* b1      = (const float*)d_in[7];
  const float* w2      = (const float*)d_in[8];
  const float* b2      = (const float*)d_in[9];
  const float* wg      = (const float*)d_in[10];
  const float* bg      = (const float*)d_in[11];
  const float* wl      = (const float*)d_in[12];
  const float* bl      = (const float*)d_in[13];
  const float* wm      = (const float*)d_in[14];
  const float* bm      = (const float*)d_in[15];
  const float* wgain   = (const float*)d_in[16];
  const float* bgain   = (const float*)d_in[17];
  const float* wgate   = (const float*)d_in[18];
  const float* bgate   = (const float*)d_in[19];
  const float* wa      = (const float*)d_in[20];
  const float* ba      = (const float*)d_in[21];
  const float* wb      = (const float*)d_in[22];
  const float* bb      = (const float*)d_in[23];
  float* out = (float*)d_out;
  float* ws  = (float*)d_ws;

  float* pm    = ws + OFF_PM;
  float* pmsq  = ws + OFF_PMSQ;
  float* rowsq = ws + OFF_ROWSQ;
  float* G     = ws + OFF_G;
  float* h0    = ws + OFF_H0;
  float* h1    = ws + OFF_H1;
  float* lcl   = ws + OFF_LOCAL;
  float* p1    = ws + OFF_P1;
  float* p2    = ws + OFF_P2;
  float* pg_   = ws + OFF_PG;
  float* part  = ws + OFF_PG;   // alias: consumed by k1 before Gp/pg_ writes
  float* Gp    = ws + OFF_PG;   // alias: written by k2 after k1, read by k3 before gemm32_gl
  float* pl_   = ws + OFF_PL;
  float* Mfin  = ws + OFF_MFIN;
  float* Cb    = ws + OFF_C;
  float* projp = ws + OFF_C;    // alias: consumed by k2_red before k8 writes Cb
  float* proj  = ws + OFF_PROJ;
  float* bT    = ws + OFF_BT;

  kT_basis<<<16,256,0,stream>>>(ibasis, bT);
  k0_colsum<<<dim3(16,NB),256,0,stream>>>(x, part, rowsq);
  k1_pmreduce<<<NB,256,0,stream>>>(part, pm, pmsq);
  k2_proj<<<dim3(512,2),256,0,stream>>>(x, bT, pm, proj, projp, G, Gp);
  k2_red<<<2048,256,0,stream>>>(proj, projp);
  k3_detail<<<NB,256,0,stream>>>(x, rowsq, G, Gp, pmsq, lng, lnb, h0);
  gemm32_partial<<<dim3(2,8),256,0,stream>>>(h0, w1, p1, 1024, 512);
  k_red_gelu<<<64,256,0,stream>>>(p1, b1, h1);
  gemm32_partial<<<dim3(2,4),256,0,stream>>>(h1, w2, p2, 512, 512);
  k_red_local<<<64,256,0,stream>>>(p2, b2, lcl);
  gemm32_gl<<<dim3(16,4,2),256,0,stream>>>(context, lcl, wg, wl, pg_, pl_);
  k7_fused<<<NB,1024,0,stream>>>(pg_, pl_, bg, bl, context, lcl, wm, bm, wgain, bgain,
                                 wgate, bgate, wa, ba, wb, bb, Mfin);
  k8_cmat<<<dim3(8,NB),256,0,stream>>>(Mfin, obasis, Cb);
  k9_out<<<dim3(16,8,NB),256,0,stream>>>(proj, Cb, out);
}

// Round 4
// 575.675 us; speedup vs baseline: 1.2503x; 1.0085x over previous
//
#include <hip/hip_runtime.h>
#include <math.h>

#define NB 32
#define NN 1024
#define ND 1024
#define NO 1024
#define NH 512
#define NR 64

// ---------------- workspace offsets (in floats) ----------------
// NOTE: colsum partials (32*16*1024 = 524288) alias OFF_PG: k0/k1 finish
// before gemm32_gl2 writes pg_ (stream-ordered), sizes match exactly.
// k2's G-partial (32768) also aliases OFF_PG (after k1; k3 consumes it
// before gemm32_gl2 writes pg_).
// k2's proj-partial (2097152) aliases OFF_C (Cb written later by k8).
#define OFF_PM     0u         /* 32768 */
#define OFF_PMSQ   32768u     /* 32 */
#define OFF_ROWSQ  32800u     /* 32768 */
#define OFF_G      65568u     /* 32768 */
#define OFF_H0     98336u     /* 32768 */
#define OFF_P1     163872u    /* 131072  w1 partials (8*32*512) */
#define OFF_P2     294944u    /* 65536   w2 partials (4*32*512) */
#define OFF_PG     360480u    /* 524288  wg partials (4*32*4096)  == colsum part == Gp */
#define OFF_PL     884768u    /* 524288 */
#define OFF_MFIN   1675424u   /* 131072 */
#define OFF_C      1806496u   /* 2097152  Cb == projp (k2 partial) */
#define OFF_PROJ   3903648u   /* 2097152 */
#define OFF_BT     6000800u   /* 65536  basisT (1024 x 64) */
/* total 6066336 floats ~= 24.27 MB (<= proven 24.5 MB) */

// compile-time float4 component select (k must be a literal under full unroll)
#define AK(av,k) ((k&3)==0?av[(k)>>2].x:((k&3)==1?av[(k)>>2].y:((k&3)==2?av[(k)>>2].z:av[(k)>>2].w)))

// ---------------- K0: column sums of pt = x[:,1:,:] + rowsq; +basis transpose blocks ----------------
__global__ __launch_bounds__(256) void k0_colsum(const float* __restrict__ x, const float* __restrict__ basis,
    float* __restrict__ part, float* __restrict__ rowsq, float* __restrict__ basisT){
  int tid = threadIdx.x;
  if(blockIdx.x == 16){
    // basis transpose: 16 of the 32 y-blocks do 64-col slices
    int yy = blockIdx.y;
    if(yy >= 16) return;
    __shared__ float s[64][65];
    int d0 = yy*64;
    #pragma unroll
    for(int i=0;i<16;i++){
      int idx = i*256 + tid;
      int r = idx>>6, dl = idx&63;
      s[r][dl] = basis[(size_t)r*ND + d0 + dl];
    }
    __syncthreads();
    #pragma unroll
    for(int i=0;i<16;i++){
      int idx = i*256 + tid;
      int dl = idx>>6, r = idx&63;
      basisT[(size_t)(d0+dl)*64 + r] = s[r][dl];
    }
    return;
  }
  __shared__ float red[4][64];
  int nseg = blockIdx.x, b = blockIdx.y;
  int d4 = tid*4;
  int lane = tid & 63, wv = tid >> 6;
  const float* xp = x + (size_t)b*NN*ND + d4;
  int nstart = nseg*64; if(nseg==0) nstart = 1;
  int nend = nseg*64 + 64;
  float sx=0.f, sy=0.f, sz=0.f, sw=0.f;
  #pragma unroll 4
  for(int n=nstart; n<nend; n++){
    float4 v = *(const float4*)&xp[(size_t)n*ND];
    sx+=v.x; sy+=v.y; sz+=v.z; sw+=v.w;
    float s = v.x*v.x + v.y*v.y + v.z*v.z + v.w*v.w;
    #pragma unroll
    for(int o=32;o>0;o>>=1) s += __shfl_down(s, o);
    if(lane==0) red[wv][n - nseg*64] = s;
  }
  *(float4*)&part[(size_t)(b*16+nseg)*1024 + d4] = make_float4(sx,sy,sz,sw);
  __syncthreads();
  if(tid < 64 && !(nseg==0 && tid==0)){
    rowsq[b*1024 + nseg*64 + tid] = red[0][tid]+red[1][tid]+red[2][tid]+red[3][tid];
  }
}

// ---------------- K1: pm = colsum/1023, pmsq[b] = sum(pm^2)/D ----------------
__global__ __launch_bounds__(256) void k1_pmreduce(const float* __restrict__ part, float* __restrict__ pm, float* __restrict__ pmsq){
  __shared__ float red[256];
  int b = blockIdx.x, tid = threadIdx.x;
  float acc = 0.f;
  #pragma unroll
  for(int i=0;i<4;i++){
    int d = i*256 + tid;
    float s = 0.f;
    #pragma unroll
    for(int ks=0;ks<16;ks++) s += part[(size_t)(b*16+ks)*1024 + d];
    float p = s * (1.0f/1023.0f);
    pm[b*1024+d] = p;
    acc += p*p;
  }
  red[tid] = acc; __syncthreads();
  for(int o=128;o>0;o>>=1){ if(tid<o) red[tid]+=red[tid+o]; __syncthreads(); }
  if(tid==0) pmsq[b] = red[0]*(1.0f/1024.0f);
}

// ---------------- K2: LDS-tiled GEMM proj = x @ basisT, k-split x2; G = x.pm partials ----------------
__global__ __launch_bounds__(256) void k2_proj(const float* __restrict__ x, const float* __restrict__ bT,
    const float* __restrict__ pm, float* __restrict__ proj, float* __restrict__ projp,
    float* __restrict__ G, float* __restrict__ Gp){
  __shared__ __align__(16) float xs[64][68];
  __shared__ __align__(16) float bs[64][68];
  int tid = threadIdx.x;
  int row0 = blockIdx.x*64;
  int b = row0 >> 10;
  int kh = blockIdx.y;               // k-half: 0 or 1
  int kbase = kh*512;
  int lrow = tid>>4, lkv = tid&15;   // staging map
  int rg = tid>>4, cg = tid&15;      // compute map
  float acc[4][4];
  #pragma unroll
  for(int i_=0;i_<4;i_++){ acc[i_][0]=0.f; acc[i_][1]=0.f; acc[i_][2]=0.f; acc[i_][3]=0.f; }
  float gp[4]={0.f,0.f,0.f,0.f};
  int sw = ((lkv>>1)&3)<<2;          // store swizzle: ((k>>3)&3)<<2 with k=4*lkv+c
  for(int kc=0;kc<8;kc++){
    int k0 = kbase + kc*64;
    float4 p4 = *(const float4*)&pm[(size_t)b*ND + k0 + lkv*4];
    #pragma unroll
    for(int i=0;i<4;i++){
      int r = lrow + 16*i;
      float4 v = *(const float4*)&x[((size_t)(row0+r))*ND + k0 + lkv*4];
      int rs = r ^ sw;
      xs[lkv*4+0][rs]=v.x; xs[lkv*4+1][rs]=v.y; xs[lkv*4+2][rs]=v.z; xs[lkv*4+3][rs]=v.w;
      gp[i] += v.x*p4.x + v.y*p4.y + v.z*p4.z + v.w*p4.w;
    }
    #pragma unroll
    for(int i=0;i<4;i++){
      int idx = tid + 256*i;         // 0..1023 float4s
      int kk = idx>>4, kv = idx&15;
      *(float4*)&bs[kk][kv*4] = *(const float4*)&bT[((size_t)(k0+kk))*64 + kv*4];
    }
    __syncthreads();
    #pragma unroll 8
    for(int kk=0;kk<64;kk++){
      float4 a = *(const float4*)&xs[kk][ (rg ^ ((kk>>3)&3)) << 2 ];
      float4 bb= *(const float4*)&bs[kk][cg*4];
      float ar[4]={a.x,a.y,a.z,a.w};
      float br[4]={bb.x,bb.y,bb.z,bb.w};
      #pragma unroll
      for(int i_=0;i_<4;i_++){
        #pragma unroll
        for(int j_=0;j_<4;j_++) acc[i_][j_] += ar[i_]*br[j_];
      }
    }
    __syncthreads();
  }
  float* dst = kh ? projp : proj;
  #pragma unroll
  for(int i_=0;i_<4;i_++){
    float4 v = make_float4(acc[i_][0],acc[i_][1],acc[i_][2],acc[i_][3]);
    *(float4*)&dst[((size_t)(row0 + rg*4 + i_))*NR + cg*4] = v;
  }
  __syncthreads();
  #pragma unroll
  for(int i=0;i<4;i++){ int r = lrow+16*i; bs[r][lkv]=gp[i]; }
  __syncthreads();
  if(tid<64){
    float g=0.f;
    #pragma unroll
    for(int c=0;c<16;c++) g += bs[tid][c];
    if(kh) Gp[row0+tid] = g; else G[row0+tid] = g;
  }
}

// ---------------- K2R: proj += projp ----------------
__global__ __launch_bounds__(256) void k2_red(float* __restrict__ proj, const float* __restrict__ projp){
  int id = blockIdx.x*256 + threadIdx.x;   // 524288 float4s
  float4 a = *(const float4*)&proj[(size_t)id*4];
  float4 p = *(const float4*)&projp[(size_t)id*4];
  a.x+=p.x; a.y+=p.y; a.z+=p.z; a.w+=p.w;
  *(float4*)&proj[(size_t)id*4] = a;
}

// ---------------- K3: scores, top-4, detail, LayerNorm -> h0 ----------------
__global__ __launch_bounds__(256) void k3_detail(const float* __restrict__ x, const float* __restrict__ rowsq,
    const float* __restrict__ G, const float* __restrict__ Gp, const float* __restrict__ pmsq,
    const float* __restrict__ gamma_, const float* __restrict__ beta_, float* __restrict__ h0){
  __shared__ float sc[1024];
  __shared__ float rv[256];
  __shared__ int ri[256];
  __shared__ int topi[4];
  __shared__ float mred[256];
  int b = blockIdx.x, tid = threadIdx.x;
  float ps = pmsq[b];
  const float invD = 1.0f/1024.0f;
  for(int n=tid;n<1024;n+=256)
    sc[n] = (n==0) ? -INFINITY : (rowsq[b*1024+n] - 2.0f*(G[b*1024+n]+Gp[b*1024+n]))*invD + ps;
  __syncthreads();
  for(int t=0;t<4;t++){
    float bv = -INFINITY; int bi = 0x7fffffff;
    for(int n=tid;n<1024;n+=256){
      float v = sc[n];
      if(v>bv || (v==bv && n<bi)){ bv=v; bi=n; }
    }
    rv[tid]=bv; ri[tid]=bi;
    __syncthreads();
    for(int o=128;o>0;o>>=1){
      if(tid<o){
        float v=rv[tid+o]; int ii=ri[tid+o];
        if(v>rv[tid] || (v==rv[tid] && ii<ri[tid])){ rv[tid]=v; ri[tid]=ii; }
      }
      __syncthreads();
    }
    if(tid==0){ topi[t]=ri[0]; sc[ri[0]] = -INFINITY; }
    __syncthreads();
  }
  int i0=topi[0], i1=topi[1], i2=topi[2], i3=topi[3];
  float dv[4]; float dsum=0.f;
  #pragma unroll
  for(int jj=0;jj<4;jj++){
    int d = tid + jj*256;
    float v = 0.25f*(x[((size_t)(b*NN+i0))*ND+d] + x[((size_t)(b*NN+i1))*ND+d]
                   + x[((size_t)(b*NN+i2))*ND+d] + x[((size_t)(b*NN+i3))*ND+d]);
    dv[jj]=v; dsum+=v;
  }
  mred[tid]=dsum; __syncthreads();
  for(int o=128;o>0;o>>=1){ if(tid<o) mred[tid]+=mred[tid+o]; __syncthreads(); }
  float mu = mred[0]*invD;
  __syncthreads();
  float vs=0.f;
  #pragma unroll
  for(int jj=0;jj<4;jj++){ float t2=dv[jj]-mu; vs+=t2*t2; }
  mred[tid]=vs; __syncthreads();
  for(int o=128;o>0;o>>=1){ if(tid<o) mred[tid]+=mred[tid+o]; __syncthreads(); }
  float var = mred[0]*invD;
  float rstd = rsqrtf(var + 1e-5f);
  #pragma unroll
  for(int jj=0;jj<4;jj++){
    int d = tid + jj*256;
    h0[b*1024+d] = (dv[jj]-mu)*rstd*gamma_[d] + beta_[d];
  }
}

// ---------------- generic small GEMM (32 x Kd) @ (Kd x Ncols), k-split partials ----------------
__global__ __launch_bounds__(256) void gemm32_partial(const float* __restrict__ V, const float* __restrict__ W,
      float* __restrict__ part, int Kd, int Ncols){
  __shared__ __align__(16) float Vs[128][36];
  int col = blockIdx.x*256 + threadIdx.x;
  int k0 = blockIdx.y*128;
  for(int i=threadIdx.x; i<4096; i+=256){ int r=i>>7, k=i&127; Vs[k][r] = V[(size_t)r*Kd + k0 + k]; }
  __syncthreads();
  float acc[32];
  #pragma unroll
  for(int r=0;r<32;r++) acc[r]=0.f;
  #pragma unroll 4
  for(int k=0;k<128;k++){
    float wv = W[(size_t)(k0+k)*Ncols + col];
    #pragma unroll
    for(int r4=0;r4<8;r4++){
      float4 v = *(const float4*)&Vs[k][r4*4];
      acc[r4*4+0]+=v.x*wv; acc[r4*4+1]+=v.y*wv; acc[r4*4+2]+=v.z*wv; acc[r4*4+3]+=v.w*wv;
    }
  }
  #pragma unroll
  for(int r=0;r<32;r++) part[((size_t)(blockIdx.y*32 + r))*Ncols + col] = acc[r];
}

// ---------------- w2 GEMM with fused gelu(b1 + sum p1) staging ----------------
__global__ __launch_bounds__(256) void gemm32_h2(const float* __restrict__ p1, const float* __restrict__ b1,
      const float* __restrict__ W, float* __restrict__ part){
  __shared__ __align__(16) float Vs[128][36];
  int col = blockIdx.x*256 + threadIdx.x;
  int k0 = blockIdx.y*128;
  for(int i=threadIdx.x; i<4096; i+=256){
    int r=i>>7, k=i&127; int j = k0 + k;
    float s = b1[j];
    #pragma unroll
    for(int ks=0;ks<8;ks++) s += p1[(size_t)(ks*32+r)*512 + j];
    Vs[k][r] = 0.5f*s*(1.0f + erff(s*0.70710678118654752440f));
  }
  __syncthreads();
  float acc[32];
  #pragma unroll
  for(int r=0;r<32;r++) acc[r]=0.f;
  #pragma unroll 4
  for(int k=0;k<128;k++){
    float wv = W[(size_t)(k0+k)*512 + col];
    #pragma unroll
    for(int r4=0;r4<8;r4++){
      float4 v = *(const float4*)&Vs[k][r4*4];
      acc[r4*4+0]+=v.x*wv; acc[r4*4+1]+=v.y*wv; acc[r4*4+2]+=v.z*wv; acc[r4*4+3]+=v.w*wv;
    }
  }
  #pragma unroll
  for(int r=0;r<32;r++) part[((size_t)(blockIdx.y*32 + r))*512 + col] = acc[r];
}

// ---------------- merged wg+wl GEMM; z=1 stages lcl = b2 + sum p2 on the fly ----------------
__global__ __launch_bounds__(256) void gemm32_gl2(const float* __restrict__ ctx, const float* __restrict__ p2,
    const float* __restrict__ b2, const float* __restrict__ wg, const float* __restrict__ wl,
    float* __restrict__ pg, float* __restrict__ pl){
  __shared__ __align__(16) float Vs[128][36];
  int z = blockIdx.z;
  int col = blockIdx.x*256 + threadIdx.x;
  int k0 = blockIdx.y*128;
  if(z == 0){
    for(int i=threadIdx.x; i<4096; i+=256){ int r=i>>7, k=i&127; Vs[k][r] = ctx[(size_t)r*512 + k0 + k]; }
  } else {
    for(int i=threadIdx.x; i<4096; i+=256){
      int r=i>>7, k=i&127; int j = k0 + k;
      float s = b2[j];
      #pragma unroll
      for(int ks=0;ks<4;ks++) s += p2[(size_t)(ks*32+r)*512 + j];
      Vs[k][r] = s;
    }
  }
  __syncthreads();
  const float* W = z ? wl : wg;
  float* part    = z ? pl : pg;
  float acc[32];
  #pragma unroll
  for(int r=0;r<32;r++) acc[r]=0.f;
  #pragma unroll 4
  for(int k=0;k<128;k++){
    float wv = W[(size_t)(k0+k)*4096 + col];
    #pragma unroll
    for(int r4=0;r4<8;r4++){
      float4 v = *(const float4*)&Vs[k][r4*4];
      acc[r4*4+0]+=v.x*wv; acc[r4*4+1]+=v.y*wv; acc[r4*4+2]+=v.z*wv; acc[r4*4+3]+=v.w*wv;
    }
  }
  #pragma unroll
  for(int r=0;r<32;r++) part[((size_t)(blockIdx.y*32 + r))*4096 + col] = acc[r];
}

// ---------------- K7 fused: heads + Ag/Al reduce + mg/ml/comm/omega + expm + Mfin ----------------
__global__ __launch_bounds__(1024) void k7_fused(
    const float* __restrict__ pg, const float* __restrict__ pl,
    const float* __restrict__ bg, const float* __restrict__ bl,
    const float* __restrict__ context, const float* __restrict__ p2, const float* __restrict__ b2v,
    const float* __restrict__ wm, const float* __restrict__ bm,
    const float* __restrict__ wgain, const float* __restrict__ bgain,
    const float* __restrict__ wgate, const float* __restrict__ bgate,
    const float* __restrict__ wa, const float* __restrict__ ba,
    const float* __restrict__ wb, const float* __restrict__ bb,
    float* __restrict__ Mfin){
  __shared__ __align__(16) float B0s[64][68];
  __shared__ __align__(16) float B1s[64][68];
  __shared__ __align__(16) float B2s[64][68];
  __shared__ float fs[1024];
  __shared__ float redm[16][64];
  __shared__ float redg[16][64];
  __shared__ float wra[16], wrb[16], wrg[16];
  __shared__ float msks[64], gainss[64];
  __shared__ float colsum[64];
  __shared__ float sABG[3];
  __shared__ int ssh;
  int b = blockIdx.x, tid = threadIdx.x;

  // ---- phase 1: stage raw Ag/Al (bias + 4 partials) into B0s/B1s ----
  int ig = tid>>5, jg = tid&31;
  int i0 = ig*2, j0 = jg*2;
  #pragma unroll
  for(int di=0;di<2;di++){
    #pragma unroll
    for(int dj=0;dj<2;dj++){
      int i=i0+di, jx=j0+dj, c=i*64+jx;
      float sg = bg[c], sl = bl[c];
      #pragma unroll
      for(int ks=0;ks<4;ks++){
        sg += pg[(size_t)(ks*32+b)*4096 + c];
        sl += pl[(size_t)(ks*32+b)*4096 + c];
      }
      B0s[i][jx] = sg; B1s[i][jx] = sl;
    }
  }
  // ---- phase 2: heads GEMV (fs[512..] = lcl on the fly from p2) ----
  if(tid < 512){
    fs[tid] = context[b*512 + tid];
  } else {
    int j2 = tid - 512;
    float s = b2v[j2];
    #pragma unroll
    for(int ks=0;ks<4;ks++) s += p2[(size_t)(ks*32+b)*512 + j2];
    fs[tid] = s;
  }
  __syncthreads();
  int j = tid & 63, kq = tid >> 6;
  {
    const float* wmp = wm    + (size_t)(kq*64)*64 + j;
    const float* wgp = wgain + (size_t)(kq*64)*64 + j;
    float am = 0.f, ag = 0.f;
    #pragma unroll 8
    for(int k=0;k<64;k++){
      float f = fs[kq*64 + k];
      am += f * wmp[k*64];
      ag += f * wgp[k*64];
    }
    redm[kq][j] = am; redg[kq][j] = ag;
    float f = fs[tid];
    float pa = f*wa[tid], pb = f*wb[tid], pgt = f*wgate[tid];
    #pragma unroll
    for(int o=32;o>0;o>>=1){
      pa += __shfl_down(pa, o);
      pb += __shfl_down(pb, o);
      pgt += __shfl_down(pgt, o);
    }
    if(j == 0){ wra[kq]=pa; wrb[kq]=pb; wrg[kq]=pgt; }
  }
  __syncthreads();
  for(int o=8;o>0;o>>=1){
    if(kq < o){ redm[kq][j] += redm[kq+o][j]; redg[kq][j] += redg[kq+o][j]; }
    __syncthreads();
  }
  if(tid < 64){
    float m = redm[0][tid] + bm[tid];
    msks[tid] = 1.0f/(1.0f+expf(-m));
    float g = redg[0][tid] + bgain[tid];
    gainss[tid] = 1.0f + 0.1f*tanhf(g);
  }
  if(tid == 0){
    float sa=0.f, sb=0.f, sg2=0.f;
    #pragma unroll
    for(int i=0;i<16;i++){ sa+=wra[i]; sb+=wrb[i]; sg2+=wrg[i]; }
    sABG[0] = 0.5f/(1.0f+expf(-(sa+ba[0])));     // alpha
    sABG[1] = 0.25f*tanhf(sb+bb[0]);             // beta
    sABG[2] = 1.0f/(1.0f+expf(-(sg2+bgate[0]))); // gate
  }
  __syncthreads();
  float alpha = sABG[0], bta = sABG[1], gate = sABG[2];
  // ---- phase 3: mg/ml (skew * mask) via regs, write back ----
  float mgr[2][2], mlr[2][2];
  #pragma unroll
  for(int di=0;di<2;di++){
    #pragma unroll
    for(int dj=0;dj<2;dj++){
      int i=i0+di, jx=j0+dj;
      float mm_ = msks[i]*msks[jx]*0.5f;
      mgr[di][dj] = mm_*(B0s[i][jx]-B0s[jx][i]);
      mlr[di][dj] = mm_*(B1s[i][jx]-B1s[jx][i]);
    }
  }
  __syncthreads();
  #pragma unroll
  for(int di=0;di<2;di++){
    #pragma unroll
    for(int dj=0;dj<2;dj++){
      int i=i0+di, jx=j0+dj;
      B0s[i][jx] = mgr[di][dj];     // mg
      B1s[i][jx] = mlr[di][dj];     // ml
    }
  }
  __syncthreads();
  // ---- phase 4: comm = ml@mg - mg@ml (2 reg-cached passes) ----
  int ir = tid>>4, cgc = tid&15;
  int jc = cgc*4;
  float4 av[16];
  {
    const float* rowp = &B1s[ir][0];           // ml row
    #pragma unroll
    for(int q=0;q<16;q++) av[q] = *(const float4*)(rowp + q*4);
    float4 t1 = make_float4(0.f,0.f,0.f,0.f);
    #pragma unroll
    for(int k=0;k<64;k++){
      float4 bv = *(const float4*)&B0s[k][jc];
      float a = AK(av,k);
      t1.x += a*bv.x; t1.y += a*bv.y; t1.z += a*bv.z; t1.w += a*bv.w;
    }
    const float* rowq = &B0s[ir][0];           // mg row
    #pragma unroll
    for(int q=0;q<16;q++) av[q] = *(const float4*)(rowq + q*4);
    float4 t2 = make_float4(0.f,0.f,0.f,0.f);
    #pragma unroll
    for(int k=0;k<64;k++){
      float4 bv = *(const float4*)&B1s[k][jc];
      float a = AK(av,k);
      t2.x += a*bv.x; t2.y += a*bv.y; t2.z += a*bv.z; t2.w += a*bv.w;
    }
    float4 cm = make_float4(t1.x-t2.x, t1.y-t2.y, t1.z-t2.z, t1.w-t2.w);
    *(float4*)&B2s[ir][jc] = cm;
  }
  __syncthreads();
  // ---- phase 5: omega in B0s ----
  {
    const float bc = bta*(1.0f/12.0f);
    float4 g4 = *(const float4*)&B0s[ir][jc];
    float4 l4 = *(const float4*)&B1s[ir][jc];
    float4 c4 = *(const float4*)&B2s[ir][jc];
    float4 o4;
    o4.x = alpha*0.5f*(g4.x+l4.x) + bc*c4.x;
    o4.y = alpha*0.5f*(g4.y+l4.y) + bc*c4.y;
    o4.z = alpha*0.5f*(g4.z+l4.z) + bc*c4.z;
    o4.w = alpha*0.5f*(g4.w+l4.w) + bc*c4.w;
    *(float4*)&B0s[ir][jc] = o4;
  }
  __syncthreads();
  // ---- phase 6: 1-norm -> scaling shift ----
  if(tid<64){
    float s=0.f;
    for(int i=0;i<64;i++) s += fabsf(B0s[i][tid]);
    colsum[tid]=s;
  }
  __syncthreads();
  if(tid==0){
    float m=0.f;
    for(int jx=0;jx<64;jx++) m = fmaxf(m, colsum[jx]);
    int s=0;
    while(m>0.5f && s<30){ m*=0.5f; s++; }
    ssh = s;
  }
  __syncthreads();
  int sh = ssh;
  float scl = ldexpf(1.0f, -sh);
  // ---- phase 7: scale omega + Horner init P = I + A/8 ----
  {
    float4 a4 = *(const float4*)&B0s[ir][jc];
    a4.x*=scl; a4.y*=scl; a4.z*=scl; a4.w*=scl;
    *(float4*)&B0s[ir][jc] = a4;
    float4 p4;
    p4.x = ((ir==jc+0)?1.0f:0.0f) + a4.x*0.125f;
    p4.y = ((ir==jc+1)?1.0f:0.0f) + a4.y*0.125f;
    p4.z = ((ir==jc+2)?1.0f:0.0f) + a4.z*0.125f;
    p4.w = ((ir==jc+3)?1.0f:0.0f) + a4.w*0.125f;
    *(float4*)&B1s[ir][jc] = p4;
  }
  __syncthreads();
  // ---- phase 8: Horner, A rows cached ONCE in regs ----
  {
    const float* rowp = &B0s[ir][0];
    #pragma unroll
    for(int q=0;q<16;q++) av[q] = *(const float4*)(rowp + q*4);
  }
  float* P = &B1s[0][0];
  float* T = &B2s[0][0];
  for(int kk=7;kk>=1;kk--){
    float4 acc = make_float4(0.f,0.f,0.f,0.f);
    #pragma unroll
    for(int k=0;k<64;k++){
      float4 bv = *(const float4*)&P[(size_t)k*68 + jc];
      float a = AK(av,k);
      acc.x += a*bv.x; acc.y += a*bv.y; acc.z += a*bv.z; acc.w += a*bv.w;
    }
    float inv = 1.0f/(float)kk;
    float4 o4;
    o4.x = ((ir==jc+0)?1.0f:0.0f) + acc.x*inv;
    o4.y = ((ir==jc+1)?1.0f:0.0f) + acc.y*inv;
    o4.z = ((ir==jc+2)?1.0f:0.0f) + acc.z*inv;
    o4.w = ((ir==jc+3)?1.0f:0.0f) + acc.w*inv;
    *(float4*)&T[(size_t)ir*68 + jc] = o4;
    __syncthreads();
    float* tmp = P; P = T; T = tmp;
  }
  // ---- phase 9: squarings ----
  float* S = (P == &B1s[0][0]) ? &B2s[0][0] : &B1s[0][0];
  for(int t=0;t<sh;t++){
    #pragma unroll
    for(int q=0;q<16;q++) av[q] = *(const float4*)(P + (size_t)ir*68 + q*4);
    float4 acc = make_float4(0.f,0.f,0.f,0.f);
    #pragma unroll
    for(int k=0;k<64;k++){
      float4 bv = *(const float4*)&P[(size_t)k*68 + jc];
      float a = AK(av,k);
      acc.x += a*bv.x; acc.y += a*bv.y; acc.z += a*bv.z; acc.w += a*bv.w;
    }
    *(float4*)&S[(size_t)ir*68 + jc] = acc;
    __syncthreads();
    float* tmp = P; P = S; S = tmp;
  }
  // ---- phase 10: Mfin = gate*(Q*gains - I) ----
  {
    float4 q4 = *(const float4*)&P[(size_t)ir*68 + jc];
    float4 v;
    v.x = gate*(q4.x*gainss[jc+0] - ((ir==jc+0)?1.0f:0.0f));
    v.y = gate*(q4.y*gainss[jc+1] - ((ir==jc+1)?1.0f:0.0f));
    v.z = gate*(q4.z*gainss[jc+2] - ((ir==jc+2)?1.0f:0.0f));
    v.w = gate*(q4.w*gainss[jc+3] - ((ir==jc+3)?1.0f:0.0f));
    *(float4*)&Mfin[(size_t)b*4096 + ir*64 + jc] = v;
  }
}

// ---------------- K8: C_b = Mfin_b @ output_basis ----------------
__global__ __launch_bounds__(256) void k8_cmat(const float* __restrict__ Mfin, const float* __restrict__ ob, float* __restrict__ C){
  __shared__ __align__(16) float MT[64][68];
  int b = blockIdx.y; int o0 = blockIdx.x*128;
  int tid = threadIdx.x;
  for(int idx=tid; idx<4096; idx+=256){ int i=idx>>6, k=idx&63; MT[k][i] = Mfin[b*4096+idx]; }
  __syncthreads();
  int cg = tid&31, rg = tid>>5;
  float acc[8][4];
  #pragma unroll
  for(int r=0;r<8;r++){ acc[r][0]=0.f; acc[r][1]=0.f; acc[r][2]=0.f; acc[r][3]=0.f; }
  for(int k=0;k<64;k++){
    float4 bv = *(const float4*)&ob[(size_t)k*NO + o0 + cg*4];
    float4 a0 = *(const float4*)&MT[k][rg*8];
    float4 a1 = *(const float4*)&MT[k][rg*8+4];
    float arr[8]={a0.x,a0.y,a0.z,a0.w,a1.x,a1.y,a1.z,a1.w};
    #pragma unroll
    for(int r=0;r<8;r++){
      acc[r][0]+=arr[r]*bv.x; acc[r][1]+=arr[r]*bv.y; acc[r][2]+=arr[r]*bv.z; acc[r][3]+=arr[r]*bv.w;
    }
  }
  #pragma unroll
  for(int r=0;r<8;r++){
    *(float4*)&C[((size_t)(b*64 + rg*8+r))*NO + o0 + cg*4] = make_float4(acc[r][0],acc[r][1],acc[r][2],acc[r][3]);
  }
}

// ---------------- K9: out_b = proj_b @ C_b  (128x128 tiles, 8x8/thread, swizzled LDS) ----------------
__global__ __launch_bounds__(256) void k9_out(const float* __restrict__ proj, const float* __restrict__ C, float* __restrict__ out){
  __shared__ __align__(16) float PT[64*128];   // PT[k][r ^ 4*(k>>2 & 7)]
  __shared__ __align__(16) float CS[64*128];   // CS[k][col ^ 4*(k>>2 & 7) ^ 4*((col>>5)&1)]
  int b = blockIdx.z; int row0 = blockIdx.y*128; int o0 = blockIdx.x*128;
  int tid = threadIdx.x;
  #pragma unroll
  for(int i=0;i<8;i++){
    int f = tid + 256*i;          // 0..2047
    int r = f>>4; int kv = f&15;  // row, k-group
    float4 v = *(const float4*)&proj[((size_t)(b*NN + row0 + r))*NR + kv*4];
    int sw = 4*(kv&7);            // = 4*(((4kv+c)>>2)&7) for c<4
    int rs = r ^ sw;
    PT[(kv*4+0)*128 + rs] = v.x;
    PT[(kv*4+1)*128 + rs] = v.y;
    PT[(kv*4+2)*128 + rs] = v.z;
    PT[(kv*4+3)*128 + rs] = v.w;
  }
  #pragma unroll
  for(int i=0;i<8;i++){
    int f = tid + 256*i;
    int k = f>>5; int kv = f&31;  // k, col-group
    int col = kv*4;
    int sc = (4*((k>>2)&7)) ^ (4*((col>>5)&1));
    *(float4*)&CS[k*128 + (col ^ sc)] =
        *(const float4*)&C[((size_t)(b*NR + k))*NO + o0 + col];
  }
  __syncthreads();
  int rg = tid>>4, cg = tid&15;
  float acc[8][8];
  #pragma unroll
  for(int r=0;r<8;r++){
    #pragma unroll
    for(int c=0;c<8;c++) acc[r][c]=0.f;
  }
  int c0 = cg*8, c1 = cg*8+4;
  int cbit = 4*((c0>>5)&1);
  for(int kg=0; kg<16; kg++){
    int swa = 4*(kg&7);
    int base = kg*4*128;
    int scb = swa ^ cbit;
    #pragma unroll
    for(int kk=0;kk<4;kk++){
      float4 a0 = *(const float4*)&PT[base + kk*128 + ((rg*8)   ^ swa)];
      float4 a1 = *(const float4*)&PT[base + kk*128 + ((rg*8+4) ^ swa)];
      float4 b0 = *(const float4*)&CS[base + kk*128 + (c0 ^ scb)];
      float4 b1 = *(const float4*)&CS[base + kk*128 + (c1 ^ scb)];
      float ar[8]={a0.x,a0.y,a0.z,a0.w,a1.x,a1.y,a1.z,a1.w};
      float br[8]={b0.x,b0.y,b0.z,b0.w,b1.x,b1.y,b1.z,b1.w};
      #pragma unroll
      for(int r=0;r<8;r++){
        #pragma unroll
        for(int c=0;c<8;c++) acc[r][c] += ar[r]*br[c];
      }
    }
  }
  #pragma unroll
  for(int r=0;r<8;r++){
    size_t rowoff = ((size_t)(b*NN + row0 + rg*8 + r))*NO + o0 + cg*8;
    *(float4*)&out[rowoff]   = make_float4(acc[r][0],acc[r][1],acc[r][2],acc[r][3]);
    *(float4*)&out[rowoff+4] = make_float4(acc[r][4],acc[r][5],acc[r][6],acc[r][7]);
  }
}

extern "C" void kernel_launch(void* const* d_in, const int* in_sizes, int n_in,
                              void* d_out, int out_size, void* d_ws, size_t ws_size,
                              hipStream_t stream) {
  (void)in_sizes; (void)n_in; (void)out_size; (void)ws_size;
  const float* x       = (const float*)d_in[0];
  const float* context = (const float*)d_in[1];
  const float* ibasis  = (const float*)d_in[2];
  const float* obasis  = (const float*)d_in[3];
  const float* lng     = (const float*)d_in[4];
  const float* lnb     = (const float*)d_in[5];
  const float* w1      = (const float*)d_in[6];
  const float* b1      = (const float*)d_in[7];
  const float* w2      = (const float*)d_in[8];
  const float* b2      = (const float*)d_in[9];
  const float* wg      = (const float*)d_in[10];
  const float* bg      = (const float*)d_in[11];
  const float* wl      = (const float*)d_in[12];
  const float* bl      = (const float*)d_in[13];
  const float* wm      = (const float*)d_in[14];
  const float* bm      = (const float*)d_in[15];
  const float* wgain   = (const float*)d_in[16];
  const float* bgain   = (const float*)d_in[17];
  const float* wgate   = (const float*)d_in[18];
  const float* bgate   = (const float*)d_in[19];
  const float* wa      = (const float*)d_in[20];
  const float* ba      = (const float*)d_in[21];
  const float* wb      = (const float*)d_in[22];
  const float* bb      = (const float*)d_in[23];
  float* out = (float*)d_out;
  float* ws  = (float*)d_ws;

  float* pm    = ws + OFF_PM;
  float* pmsq  = ws + OFF_PMSQ;
  float* rowsq = ws + OFF_ROWSQ;
  float* G     = ws + OFF_G;
  float* h0    = ws + OFF_H0;
  float* p1    = ws + OFF_P1;
  float* p2    = ws + OFF_P2;
  float* pg_   = ws + OFF_PG;
  float* part  = ws + OFF_PG;   // alias: consumed by k1 before Gp/pg_ writes
  float* Gp    = ws + OFF_PG;   // alias: written by k2 after k1, read by k3 before gemm32_gl2
  float* pl_   = ws + OFF_PL;
  float* Mfin  = ws + OFF_MFIN;
  float* Cb    = ws + OFF_C;
  float* projp = ws + OFF_C;    // alias: consumed by k2_red before k8 writes Cb
  float* proj  = ws + OFF_PROJ;
  float* bT    = ws + OFF_BT;

  k0_colsum<<<dim3(17,NB),256,0,stream>>>(x, ibasis, part, rowsq, bT);
  k1_pmreduce<<<NB,256,0,stream>>>(part, pm, pmsq);
  k2_proj<<<dim3(512,2),256,0,stream>>>(x, bT, pm, proj, projp, G, Gp);
  k2_red<<<2048,256,0,stream>>>(proj, projp);
  k3_detail<<<NB,256,0,stream>>>(x, rowsq, G, Gp, pmsq, lng, lnb, h0);
  gemm32_partial<<<dim3(2,8),256,0,stream>>>(h0, w1, p1, 1024, 512);
  gemm32_h2<<<dim3(2,4),256,0,stream>>>(p1, b1, w2, p2);
  gemm32_gl2<<<dim3(16,4,2),256,0,stream>>>(context, p2, b2, wg, wl, pg_, pl_);
  k7_fused<<<NB,1024,0,stream>>>(pg_, pl_, bg, bl, context, p2, b2, wm, bm, wgain, bgain,
                                 wgate, bgate, wa, ba, wb, bb, Mfin);
  k8_cmat<<<dim3(8,NB),256,0,stream>>>(Mfin, obasis, Cb);
  k9_out<<<dim3(8,8,NB),256,0,stream>>>(proj, Cb, out);
}